// Round 12
// baseline (985.464 us; speedup 1.0000x reference)
//
#include <hip/hip_runtime.h>
#include <hip/hip_bf16.h>

// Problem constants (fixed by reference setup)
#define NN     10000      // variable nodes
#define NF     80000      // factors
#define NE     160000     // directed edges per direction
#define SDIM   64         // state dim
#define HMDIM  128        // hidden (message MLP)
#define HRDIM  128        // hidden (readout)
#define KIN    136        // 2*S + 8
#define NSTEPS 5

static_assert(NE % 64 == 0, "edge grid exact");

typedef __attribute__((ext_vector_type(8))) short short8;   // 8 bf16 = 4 VGPRs
typedef __attribute__((ext_vector_type(4))) float f32x4;    // MFMA C/D

// ---------- helpers ----------
static __device__ __forceinline__ float bf2f(unsigned short u) {
    return __uint_as_float(((unsigned int)u) << 16);
}
// R4 lesson: PURE fp16 fails absmax (0.076 vs 0.0157); 3-MFMA bf16 hi/lo
// (~16 bits/operand) gives 0.0039 — the numerics floor, keep it.
// R9 lesson: per-wave direct-global B reads for the edge MLP are latency/
// L2-bound; staged-LDS B is right for the edge MLP, direct-global only at
// the GRU's MFMA:bytes ratio.
// R12: ONE barrier per phase. The trailing (read-done) barrier is redundant
// once STAGE(next) is issued AFTER the entry barrier: buf[(p+1)&1]'s last
// readers were phase p-1's MFMAs, and every wave passing the entry barrier
// of phase p has already consumed its phase p-1 ds_reads (program order).
static __device__ __forceinline__ unsigned short f2bf(float f) {
    __hip_bfloat16 h = __float2bfloat16(f);
    unsigned short u;
    __builtin_memcpy(&u, &h, 2);
    return u;
}
static __device__ __forceinline__ float sigm(float x) {
    x = fminf(fmaxf(x, -30.f), 30.f);
    return 1.f / (1.f + __expf(-x));
}
static __device__ __forceinline__ float tanh_f(float x) {
    x = fminf(fmaxf(x, -15.f), 15.f);
    float t = __expf(2.f * x);
    return (t - 1.f) / (t + 1.f);
}
// split f32 -> bf16 hi + bf16 lo (x ~= hi + lo, ~16 mantissa bits kept)
static __device__ __forceinline__ void split8(const float* x, short8& hi, short8& lo) {
    #pragma unroll
    for (int i = 0; i < 8; ++i) {
        unsigned short h = f2bf(x[i]);
        hi[i] = (short)h;
        lo[i] = (short)f2bf(x[i] - bf2f(h));
    }
}
static __device__ __forceinline__ void f4pair_to8(float4 a, float4 b, float* xv) {
    xv[0]=a.x; xv[1]=a.y; xv[2]=a.z; xv[3]=a.w;
    xv[4]=b.x; xv[5]=b.y; xv[6]=b.z; xv[7]=b.w;
}
// async global->LDS DMA, 16B per lane, no VGPR round-trip (tracked by vmcnt)
static __device__ __forceinline__ void dma16(const unsigned short* g, unsigned short* l) {
    __builtin_amdgcn_global_load_lds(
        (const __attribute__((address_space(1))) void*)g,
        (__attribute__((address_space(3))) void*)l,
        16, 0, 0);
}

#define LGKM0() asm volatile("s_waitcnt lgkmcnt(0)" ::: "memory")
#define VMC0()  asm volatile("s_waitcnt vmcnt(0)"   ::: "memory")
#define SBAR()  __builtin_amdgcn_s_barrier()
#define SCHED0() __builtin_amdgcn_sched_barrier(0)
#define PRIO1() __builtin_amdgcn_s_setprio(1)
#define PRIO0() __builtin_amdgcn_s_setprio(0)

__global__ void k_zero(float* __restrict__ p, int n) {
    int i = blockIdx.x * blockDim.x + threadIdx.x;
    int stride = gridDim.x * blockDim.x;
    for (; i < n; i += stride) p[i] = 0.f;
}

// ---------- weight transpose for readout (dst[k][j] = src[j][k]) ----------
#define NTR 2
struct TArgs {
    const float* src[NTR];
    float*       dst[NTR];
    int          R[NTR];
    int          C[NTR];
};
__global__ void k_transpose(TArgs a) {
    const int b = blockIdx.x;
    const float* s = a.src[b];
    float* d = a.dst[b];
    const int R = a.R[b], C = a.C[b], n = R * C;
    for (int i = threadIdx.x; i < n; i += blockDim.x) {
        int r = i / C, c = i % C;
        d[c * R + r] = s[i];
    }
}

// ---------- pack weights into B-fragment streams (hi/lo bf16) ----------
#define NPK 10
struct PArgs {
    const float*    src[NPK];
    unsigned short* hi[NPK];
    unsigned short* lo[NPK];
    int             N[NPK], K[NPK], CK[NPK];
};
__global__ void k_pack(PArgs a) {
    const int b = blockIdx.x;
    const float* s = a.src[b];
    unsigned short* ph = a.hi[b];
    unsigned short* pl = a.lo[b];
    const int N = a.N[b], K = a.K[b], CK = a.CK[b];
    const int NT = N >> 4;
    const int total = NT * CK * 512;
    for (int i = threadIdx.x; i < total; i += blockDim.x) {
        int j    = i & 7;
        int ln   = (i >> 3) & 63;
        int tile = i >> 9;
        int tn   = tile % NT;
        int ck   = tile / NT;
        int k = ck * 32 + ((ln >> 4) * 8) + j;
        int n = tn * 16 + (ln & 15);
        float f = (k < K) ? s[n * K + k] : 0.f;
        unsigned short h = f2bf(f);
        ph[i] = h;
        pl[i] = f2bf(f - bf2f(h));
    }
}

// bias sums for GRU r/z gates: o[j] = bih[j] + bhh[j], j in [0,192)
__global__ void k_bsum(const float* bih0, const float* bhh0, float* o0,
                       const float* bih1, const float* bhh1, float* o1) {
    int i = threadIdx.x;
    if (i < 192) { o0[i] = bih0[i] + bhh0[i]; o1[i] = bih1[i] + bhh1[i]; }
}

// ---- half-phase B staging: 4KB hi + 4KB lo per half-phase, dbuf 16KB ----
#define STAGE(buf, sh, sl) do {                                            \
    const int u0_ = wv * 2;                                                \
    _Pragma("unroll")                                                      \
    for (int k_ = 0; k_ < 2; ++k_) {                                       \
        const int u_ = u0_ + k_;                                           \
        const unsigned short* s_ = (u_ < 4 ? (sh) : (sl)) + (u_ & 3) * 512;\
        unsigned short* d_ = (u_ < 4 ? &BH[buf][0] : &BL[buf][0]) + (u_ & 3) * 512; \
        dma16(s_ + lane * 8, d_);                                          \
    }                                                                      \
} while (0)

// single-barrier phase prologue: wait own-phase DMAs, sync, then (caller
// issues next STAGE + MFMAs). vmcnt(0) is exact: only the current phase's
// 2 DMAs are outstanding here (next phase's stage not yet issued).
#define PHASE_SYNC() do { VMC0(); LGKM0(); SBAR(); SCHED0(); } while (0)

// ---------- f2v MFMA edge MLP + atomic scatter ----------
// R12: one barrier per phase (22 total vs 44). Phase body:
// {A-prep; PHASE_SYNC; STAGE(next); MFMA(cur)}.
__global__ __launch_bounds__(256, 3)
void k_edge_mfma(const float* __restrict__ hrow, const float* __restrict__ hcol,
                 const int* __restrict__ cols,
                 const float* __restrict__ feat,
                 const unsigned short* __restrict__ w1h, const unsigned short* __restrict__ w1l,
                 const unsigned short* __restrict__ w2h, const unsigned short* __restrict__ w2l,
                 const unsigned short* __restrict__ w3h, const unsigned short* __restrict__ w3l,
                 const float* __restrict__ b1, const float* __restrict__ b2,
                 const float* __restrict__ b3,
                 float* __restrict__ nm)
{
    __shared__ __align__(16) unsigned short Hhi[64][136];   // 17.0 KB
    __shared__ __align__(16) unsigned short Hlo[64][136];   // 17.0 KB
    __shared__ __align__(16) unsigned short BH[2][2048];    // 8 KB (dbuf hi)
    __shared__ __align__(16) unsigned short BL[2][2048];    // 8 KB (dbuf lo)
    const int lane = threadIdx.x & 63;
    const int wv   = threadIdx.x >> 6;        // 0..3
    const int quad = lane >> 4;               // 0..3
    const int col  = lane & 15;

    const int e0 = blockIdx.x * 64 + wv * 16 + col;
    const int r0 = e0 >> 1;                   // f2v rows = fidx = e/2
    const int c0 = cols[e0];

    float4 gR[4], gC[4], gFr, gFc;
    {
        const float4* pr = (const float4*)(hrow + (size_t)r0 * 64);
        const float4* pc = (const float4*)(hcol + (size_t)c0 * 64);
        gR[0] = pr[quad * 2];     gR[1] = pr[quad * 2 + 1];
        gR[2] = pr[8 + quad * 2]; gR[3] = pr[8 + quad * 2 + 1];
        gC[0] = pc[quad * 2];     gC[1] = pc[quad * 2 + 1];
        gC[2] = pc[8 + quad * 2]; gC[3] = pc[8 + quad * 2 + 1];
        gFr = *(const float4*)(feat + (size_t)r0 * 4);
        gFc = *(const float4*)(feat + (size_t)c0 * 4);
    }
    int cc[4];
    #pragma unroll
    for (int rr = 0; rr < 4; ++rr)
        cc[rr] = cols[blockIdx.x * 64 + wv * 16 + quad * 4 + rr];

    float b1v[8], b2v[8], b3v[4];
    #pragma unroll
    for (int t = 0; t < 8; ++t) { b1v[t] = b1[t * 16 + col]; b2v[t] = b2[t * 16 + col]; }
    #pragma unroll
    for (int t = 0; t < 4; ++t) b3v[t] = b3[t * 16 + col];

    VMC0(); SCHED0();      // drain: vmcnt queue now carries ONLY staging DMAs
    STAGE(0, w1h, w1l);    // phase-0 data in flight

    f32x4 acc[8];
    #pragma unroll
    for (int t = 0; t < 8; ++t) acc[t] = (f32x4){0.f, 0.f, 0.f, 0.f};

    short8 ahi, alo;
    // ---- layer 1: K = 136 padded to 160 -> phases 0..9 ----
    #pragma unroll
    for (int hp = 0; hp < 10; ++hp) {
        if ((hp & 1) == 0) {                  // chunk boundary: new A frags
            const int ck = hp >> 1;
            float xv[8];
            if (ck < 2)      f4pair_to8(gR[ck * 2], gR[ck * 2 + 1], xv);
            else if (ck < 4) f4pair_to8(gC[(ck - 2) * 2], gC[(ck - 2) * 2 + 1], xv);
            else if (quad == 0) f4pair_to8(gFr, gFc, xv);
            else {
                #pragma unroll
                for (int i = 0; i < 8; ++i) xv[i] = 0.f;
            }
            split8(xv, ahi, alo);
        }
        PHASE_SYNC();                         // phase-hp staging complete
        {
            const unsigned short* nh; const unsigned short* nl;
            if (hp < 9) { nh = w1h + (hp + 1) * 2048; nl = w1l + (hp + 1) * 2048; }
            else        { nh = w2h;                   nl = w2l; }
            STAGE((hp + 1) & 1, nh, nl);      // safe: buf's last readers were
        }                                     // phase hp-1, done before SBAR
        {
            const unsigned short* bh = &BH[hp & 1][0];
            const unsigned short* bl = &BL[hp & 1][0];
            #pragma unroll
            for (int t = 0; t < 4; ++t) {
                const int tn = (hp & 1) * 4 + t;
                short8 bhi = *(const short8*)(bh + t * 512 + lane * 8);
                short8 blo = *(const short8*)(bl + t * 512 + lane * 8);
                acc[tn] = __builtin_amdgcn_mfma_f32_16x16x32_bf16(ahi, bhi, acc[tn], 0, 0, 0);
                acc[tn] = __builtin_amdgcn_mfma_f32_16x16x32_bf16(ahi, blo, acc[tn], 0, 0, 0);
                acc[tn] = __builtin_amdgcn_mfma_f32_16x16x32_bf16(alo, bhi, acc[tn], 0, 0, 0);
            }
        }
    }
    // epilogue 1: bias + relu -> H (bf16 hi/lo), wave-private rows
    #pragma unroll
    for (int tn = 0; tn < 8; ++tn)
        #pragma unroll
        for (int rr = 0; rr < 4; ++rr) {
            float v = fmaxf(acc[tn][rr] + b1v[tn], 0.f);
            int m = wv * 16 + quad * 4 + rr;
            unsigned short h = f2bf(v);
            Hhi[m][tn * 16 + col] = h;
            Hlo[m][tn * 16 + col] = f2bf(v - bf2f(h));
        }

    // ---- layer 2: K = 128 -> phases 10..17 ----
    #pragma unroll
    for (int t = 0; t < 8; ++t) acc[t] = (f32x4){0.f, 0.f, 0.f, 0.f};
    const int m0 = wv * 16 + col;
    #pragma unroll
    for (int h2 = 0; h2 < 8; ++h2) {
        const int hp = 10 + h2;
        if ((h2 & 1) == 0) {                  // chunk boundary: A from H (own rows)
            const int ck = h2 >> 1;
            ahi = *(const short8*)(&Hhi[m0][ck * 32 + quad * 8]);
            alo = *(const short8*)(&Hlo[m0][ck * 32 + quad * 8]);
        }
        PHASE_SYNC();
        {
            const unsigned short* nh; const unsigned short* nl;
            if (h2 < 7) { nh = w2h + (h2 + 1) * 2048; nl = w2l + (h2 + 1) * 2048; }
            else        { nh = w3h;                   nl = w3l; }
            STAGE((hp + 1) & 1, nh, nl);
        }
        {
            const unsigned short* bh = &BH[hp & 1][0];
            const unsigned short* bl = &BL[hp & 1][0];
            #pragma unroll
            for (int t = 0; t < 4; ++t) {
                const int tn = (h2 & 1) * 4 + t;
                short8 bhi = *(const short8*)(bh + t * 512 + lane * 8);
                short8 blo = *(const short8*)(bl + t * 512 + lane * 8);
                acc[tn] = __builtin_amdgcn_mfma_f32_16x16x32_bf16(ahi, bhi, acc[tn], 0, 0, 0);
                acc[tn] = __builtin_amdgcn_mfma_f32_16x16x32_bf16(ahi, blo, acc[tn], 0, 0, 0);
                acc[tn] = __builtin_amdgcn_mfma_f32_16x16x32_bf16(alo, bhi, acc[tn], 0, 0, 0);
            }
        }
    }
    // epilogue 2 (wave-private H rows)
    #pragma unroll
    for (int tn = 0; tn < 8; ++tn)
        #pragma unroll
        for (int rr = 0; rr < 4; ++rr) {
            float v = fmaxf(acc[tn][rr] + b2v[tn], 0.f);
            int m = wv * 16 + quad * 4 + rr;
            unsigned short h = f2bf(v);
            Hhi[m][tn * 16 + col] = h;
            Hlo[m][tn * 16 + col] = f2bf(v - bf2f(h));
        }

    // ---- layer 3: N = 64, K = 128 -> phases 18..21 (1 chunk each) ----
    f32x4 a3[4];
    #pragma unroll
    for (int t = 0; t < 4; ++t) a3[t] = (f32x4){0.f, 0.f, 0.f, 0.f};
    #pragma unroll
    for (int h3 = 0; h3 < 4; ++h3) {
        const int hp = 18 + h3;
        short8 a3h = *(const short8*)(&Hhi[m0][h3 * 32 + quad * 8]);
        short8 a3l = *(const short8*)(&Hlo[m0][h3 * 32 + quad * 8]);
        PHASE_SYNC();
        if (h3 < 3) STAGE((hp + 1) & 1, w3h + (h3 + 1) * 2048, w3l + (h3 + 1) * 2048);
        {
            const unsigned short* bh = &BH[hp & 1][0];
            const unsigned short* bl = &BL[hp & 1][0];
            #pragma unroll
            for (int t = 0; t < 4; ++t) {
                short8 bhi = *(const short8*)(bh + t * 512 + lane * 8);
                short8 blo = *(const short8*)(bl + t * 512 + lane * 8);
                a3[t] = __builtin_amdgcn_mfma_f32_16x16x32_bf16(a3h, bhi, a3[t], 0, 0, 0);
                a3[t] = __builtin_amdgcn_mfma_f32_16x16x32_bf16(a3h, blo, a3[t], 0, 0, 0);
                a3[t] = __builtin_amdgcn_mfma_f32_16x16x32_bf16(a3l, bhi, a3[t], 0, 0, 0);
            }
        }
    }

    #pragma unroll
    for (int tn = 0; tn < 4; ++tn) {
        float bias = b3v[tn];
        #pragma unroll
        for (int rr = 0; rr < 4; ++rr)
            atomicAdd(&nm[(size_t)cc[rr] * 64 + tn * 16 + col], a3[tn][rr] + bias);
    }
}

// ---------- FUSED v2f edge MLP + fac GRU ----------
// (R11 structure, measured 85.6us; R12 adds single-barrier phases + gl
// stride 260->261 to kill the 8-way combine-read bank conflict.)
__global__ __launch_bounds__(256, 3)
void k_edge_gru_fused(const float* __restrict__ hrow, float* fstate,
                      const int* __restrict__ rows,
                      const float* __restrict__ feat,
                      const unsigned short* __restrict__ w1h, const unsigned short* __restrict__ w1l,
                      const unsigned short* __restrict__ w2h, const unsigned short* __restrict__ w2l,
                      const unsigned short* __restrict__ w3h, const unsigned short* __restrict__ w3l,
                      const float* __restrict__ b1, const float* __restrict__ b2,
                      const float* __restrict__ b3,
                      const unsigned short* __restrict__ gih_h, const unsigned short* __restrict__ gih_l,
                      const unsigned short* __restrict__ ghh_h, const unsigned short* __restrict__ ghh_l,
                      const float* __restrict__ bsum, const float* __restrict__ bih,
                      const float* __restrict__ bhh)
{
    // 51200B arena. Phase-1: Hhi|Hlo|BH|BL. Phase-2 overlays (behind
    // barrier A): nmL = [0,8704) float[32][68]; gl = [8704,42112)
    // float[32][261] (stride 261: 261%32=5, coprime -> conflict-free).
    __shared__ __align__(16) unsigned char SM[51200];
    unsigned short (*Hhi)[136] = (unsigned short(*)[136])(SM);
    unsigned short (*Hlo)[136] = (unsigned short(*)[136])(SM + 17408);
    unsigned short (*BH)[2048] = (unsigned short(*)[2048])(SM + 34816);
    unsigned short (*BL)[2048] = (unsigned short(*)[2048])(SM + 43008);
    float (*nmL)[68]  = (float(*)[68])(SM);
    float (*gl)[261]  = (float(*)[261])(SM + 8704);

    const int lane = threadIdx.x & 63;
    const int wv   = threadIdx.x >> 6;        // 0..3
    const int quad = lane >> 4;               // 0..3
    const int col  = lane & 15;

    const int e0 = blockIdx.x * 64 + wv * 16 + col;
    const int r0 = rows[e0];                  // variable endpoint
    const int c0 = e0 >> 1;                   // v2f cols = fidx = e/2

    float4 gR[4], gC[4], gFr, gFc;
    {
        const float4* pr = (const float4*)(hrow + (size_t)r0 * 64);
        const float4* pc = (const float4*)(fstate + (size_t)c0 * 64);
        gR[0] = pr[quad * 2];     gR[1] = pr[quad * 2 + 1];
        gR[2] = pr[8 + quad * 2]; gR[3] = pr[8 + quad * 2 + 1];
        gC[0] = pc[quad * 2];     gC[1] = pc[quad * 2 + 1];
        gC[2] = pc[8 + quad * 2]; gC[3] = pc[8 + quad * 2 + 1];
        gFr = *(const float4*)(feat + (size_t)r0 * 4);
        gFc = *(const float4*)(feat + (size_t)c0 * 4);
    }
    float b1v[8], b2v[8], b3v[4];
    #pragma unroll
    for (int t = 0; t < 8; ++t) { b1v[t] = b1[t * 16 + col]; b2v[t] = b2[t * 16 + col]; }
    #pragma unroll
    for (int t = 0; t < 4; ++t) b3v[t] = b3[t * 16 + col];

    VMC0(); SCHED0();
    STAGE(0, w1h, w1l);

    f32x4 acc[8];
    #pragma unroll
    for (int t = 0; t < 8; ++t) acc[t] = (f32x4){0.f, 0.f, 0.f, 0.f};

    short8 ahi, alo;
    #pragma unroll
    for (int hp = 0; hp < 10; ++hp) {
        if ((hp & 1) == 0) {
            const int ck = hp >> 1;
            float xv[8];
            if (ck < 2)      f4pair_to8(gR[ck * 2], gR[ck * 2 + 1], xv);
            else if (ck < 4) f4pair_to8(gC[(ck - 2) * 2], gC[(ck - 2) * 2 + 1], xv);
            else if (quad == 0) f4pair_to8(gFr, gFc, xv);
            else {
                #pragma unroll
                for (int i = 0; i < 8; ++i) xv[i] = 0.f;
            }
            split8(xv, ahi, alo);
        }
        PHASE_SYNC();
        {
            const unsigned short* nh; const unsigned short* nl;
            if (hp < 9) { nh = w1h + (hp + 1) * 2048; nl = w1l + (hp + 1) * 2048; }
            else        { nh = w2h;                   nl = w2l; }
            STAGE((hp + 1) & 1, nh, nl);
        }
        {
            const unsigned short* bh = &BH[hp & 1][0];
            const unsigned short* bl = &BL[hp & 1][0];
            #pragma unroll
            for (int t = 0; t < 4; ++t) {
                const int tn = (hp & 1) * 4 + t;
                short8 bhi = *(const short8*)(bh + t * 512 + lane * 8);
                short8 blo = *(const short8*)(bl + t * 512 + lane * 8);
                acc[tn] = __builtin_amdgcn_mfma_f32_16x16x32_bf16(ahi, bhi, acc[tn], 0, 0, 0);
                acc[tn] = __builtin_amdgcn_mfma_f32_16x16x32_bf16(ahi, blo, acc[tn], 0, 0, 0);
                acc[tn] = __builtin_amdgcn_mfma_f32_16x16x32_bf16(alo, bhi, acc[tn], 0, 0, 0);
            }
        }
    }
    #pragma unroll
    for (int tn = 0; tn < 8; ++tn)
        #pragma unroll
        for (int rr = 0; rr < 4; ++rr) {
            float v = fmaxf(acc[tn][rr] + b1v[tn], 0.f);
            int m = wv * 16 + quad * 4 + rr;
            unsigned short h = f2bf(v);
            Hhi[m][tn * 16 + col] = h;
            Hlo[m][tn * 16 + col] = f2bf(v - bf2f(h));
        }

    #pragma unroll
    for (int t = 0; t < 8; ++t) acc[t] = (f32x4){0.f, 0.f, 0.f, 0.f};
    const int m0 = wv * 16 + col;
    #pragma unroll
    for (int h2 = 0; h2 < 8; ++h2) {
        const int hp = 10 + h2;
        if ((h2 & 1) == 0) {
            const int ck = h2 >> 1;
            ahi = *(const short8*)(&Hhi[m0][ck * 32 + quad * 8]);
            alo = *(const short8*)(&Hlo[m0][ck * 32 + quad * 8]);
        }
        PHASE_SYNC();
        {
            const unsigned short* nh; const unsigned short* nl;
            if (h2 < 7) { nh = w2h + (h2 + 1) * 2048; nl = w2l + (h2 + 1) * 2048; }
            else        { nh = w3h;                   nl = w3l; }
            STAGE((hp + 1) & 1, nh, nl);
        }
        {
            const unsigned short* bh = &BH[hp & 1][0];
            const unsigned short* bl = &BL[hp & 1][0];
            #pragma unroll
            for (int t = 0; t < 4; ++t) {
                const int tn = (h2 & 1) * 4 + t;
                short8 bhi = *(const short8*)(bh + t * 512 + lane * 8);
                short8 blo = *(const short8*)(bl + t * 512 + lane * 8);
                acc[tn] = __builtin_amdgcn_mfma_f32_16x16x32_bf16(ahi, bhi, acc[tn], 0, 0, 0);
                acc[tn] = __builtin_amdgcn_mfma_f32_16x16x32_bf16(ahi, blo, acc[tn], 0, 0, 0);
                acc[tn] = __builtin_amdgcn_mfma_f32_16x16x32_bf16(alo, bhi, acc[tn], 0, 0, 0);
            }
        }
    }
    #pragma unroll
    for (int tn = 0; tn < 8; ++tn)
        #pragma unroll
        for (int rr = 0; rr < 4; ++rr) {
            float v = fmaxf(acc[tn][rr] + b2v[tn], 0.f);
            int m = wv * 16 + quad * 4 + rr;
            unsigned short h = f2bf(v);
            Hhi[m][tn * 16 + col] = h;
            Hlo[m][tn * 16 + col] = f2bf(v - bf2f(h));
        }

    f32x4 a3[4];
    #pragma unroll
    for (int t = 0; t < 4; ++t) a3[t] = (f32x4){0.f, 0.f, 0.f, 0.f};
    #pragma unroll
    for (int h3 = 0; h3 < 4; ++h3) {
        const int hp = 18 + h3;
        short8 a3h = *(const short8*)(&Hhi[m0][h3 * 32 + quad * 8]);
        short8 a3l = *(const short8*)(&Hlo[m0][h3 * 32 + quad * 8]);
        PHASE_SYNC();
        if (h3 < 3) STAGE((hp + 1) & 1, w3h + (h3 + 1) * 2048, w3l + (h3 + 1) * 2048);
        {
            const unsigned short* bh = &BH[hp & 1][0];
            const unsigned short* bl = &BL[hp & 1][0];
            #pragma unroll
            for (int t = 0; t < 4; ++t) {
                short8 bhi = *(const short8*)(bh + t * 512 + lane * 8);
                short8 blo = *(const short8*)(bl + t * 512 + lane * 8);
                a3[t] = __builtin_amdgcn_mfma_f32_16x16x32_bf16(a3h, bhi, a3[t], 0, 0, 0);
                a3[t] = __builtin_amdgcn_mfma_f32_16x16x32_bf16(a3h, blo, a3[t], 0, 0, 0);
                a3[t] = __builtin_amdgcn_mfma_f32_16x16x32_bf16(a3l, bhi, a3[t], 0, 0, 0);
            }
        }
    }

    // ---- barrier A: every wave done with H/B reads -> overlays safe
    LGKM0(); SBAR(); SCHED0();

    // pairsum -> nmL (factor message tile, rows = local factor 0..31)
    {
        int lf0 = wv * 8 + quad * 2;
        #pragma unroll
        for (int tn = 0; tn < 4; ++tn) {
            float b2x = 2.f * b3v[tn];
            nmL[lf0][tn * 16 + col]     = a3[tn][0] + a3[tn][1] + b2x;
            nmL[lf0 + 1][tn * 16 + col] = a3[tn][2] + a3[tn][3] + b2x;
        }
    }
    LGKM0(); SBAR(); SCHED0();   // barrier B: nmL visible to all waves

    // ---- fused fac GRU: 32 factors, wave = (Mhalf mt, Nhalf half) ----
    const int fbase = blockIdx.x * 32;
    const int mt    = wv >> 1;             // 16-row M-tile
    const int half  = wv & 1;              // gate-tile half (6 of 12)
    const int hrow0 = fbase + mt * 16 + col;

    if (half == 0) {
        f32x4 rz6[6];
        #pragma unroll
        for (int i = 0; i < 6; ++i) rz6[i] = (f32x4){0.f, 0.f, 0.f, 0.f};
        #pragma unroll
        for (int ck = 0; ck < 2; ++ck) {
            short8 mhi, mlo, hhi, hlo;
            {
                float xv[8];
                *(float4*)&xv[0] = *(const float4*)(&nmL[mt * 16 + col][ck * 32 + quad * 8]);
                *(float4*)&xv[4] = *(const float4*)(&nmL[mt * 16 + col][ck * 32 + quad * 8 + 4]);
                split8(xv, mhi, mlo);
                const float* hp_ = fstate + (size_t)hrow0 * 64 + ck * 32 + quad * 8;
                *(float4*)&xv[0] = *(const float4*)(hp_);
                *(float4*)&xv[4] = *(const float4*)(hp_ + 4);
                split8(xv, hhi, hlo);
            }
            const unsigned short* ih = gih_h + (size_t)(ck * 12) * 512 + lane * 8;
            const unsigned short* il = gih_l + (size_t)(ck * 12) * 512 + lane * 8;
            const unsigned short* hh = ghh_h + (size_t)(ck * 12) * 512 + lane * 8;
            const unsigned short* hl = ghh_l + (size_t)(ck * 12) * 512 + lane * 8;
            #pragma unroll
            for (int i = 0; i < 6; ++i) {
                short8 bihh = *(const short8*)(ih + i * 512);
                short8 bihl = *(const short8*)(il + i * 512);
                short8 bhhh = *(const short8*)(hh + i * 512);
                short8 bhhl = *(const short8*)(hl + i * 512);
                rz6[i] = __builtin_amdgcn_mfma_f32_16x16x32_bf16(mhi, bihh, rz6[i], 0, 0, 0);
                rz6[i] = __builtin_amdgcn_mfma_f32_16x16x32_bf16(mhi, bihl, rz6[i], 0, 0, 0);
                rz6[i] = __builtin_amdgcn_mfma_f32_16x16x32_bf16(mlo, bihh, rz6[i], 0, 0, 0);
                rz6[i] = __builtin_amdgcn_mfma_f32_16x16x32_bf16(hhi, bhhh, rz6[i], 0, 0, 0);
                rz6[i] = __builtin_amdgcn_mfma_f32_16x16x32_bf16(hhi, bhhl, rz6[i], 0, 0, 0);
                rz6[i] = __builtin_amdgcn_mfma_f32_16x16x32_bf16(hlo, bhhh, rz6[i], 0, 0, 0);
            }
        }
        #pragma unroll
        for (int i = 0; i < 6; ++i)
            #pragma unroll
            for (int rr = 0; rr < 4; ++rr)
                gl[mt * 16 + quad * 4 + rr][i * 16 + col] = rz6[i][rr];
    } else {
        f32x4 rz2[2], niA[4], nhA[4];
        #pragma unroll
        for (int i = 0; i < 2; ++i) rz2[i] = (f32x4){0.f, 0.f, 0.f, 0.f};
        #pragma unroll
        for (int i = 0; i < 4; ++i) {
            niA[i] = (f32x4){0.f, 0.f, 0.f, 0.f};
            nhA[i] = (f32x4){0.f, 0.f, 0.f, 0.f};
        }
        #pragma unroll
        for (int ck = 0; ck < 2; ++ck) {
            short8 mhi, mlo, hhi, hlo;
            {
                float xv[8];
                *(float4*)&xv[0] = *(const float4*)(&nmL[mt * 16 + col][ck * 32 + quad * 8]);
                *(float4*)&xv[4] = *(const float4*)(&nmL[mt * 16 + col][ck * 32 + quad * 8 + 4]);
                split8(xv, mhi, mlo);
                const float* hp_ = fstate + (size_t)hrow0 * 64 + ck * 32 + quad * 8;
                *(float4*)&xv[0] = *(const float4*)(hp_);
                *(float4*)&xv[4] = *(const float4*)(hp_ + 4);
                split8(xv, hhi, hlo);
            }
            const unsigned short* ih = gih_h + (size_t)(ck * 12) * 512 + lane * 8;
            const unsigned short* il = gih_l + (size_t)(ck * 12) * 512 + lane * 8;
            const unsigned short* hh = ghh_h + (size_t)(ck * 12) * 512 + lane * 8;
            const unsigned short* hl = ghh_l + (size_t)(ck * 12) * 512 + lane * 8;
            #pragma unroll
            for (int i = 0; i < 2; ++i) {          // rz tiles 6,7
                const int tn = 6 + i;
                short8 bihh = *(const short8*)(ih + tn * 512);
                short8 bihl = *(const short8*)(il + tn * 512);
                short8 bhhh = *(const short8*)(hh + tn * 512);
                short8 bhhl = *(const short8*)(hl + tn * 512);
                rz2[i] = __builtin_amdgcn_mfma_f32_16x16x32_bf16(mhi, bihh, rz2[i], 0, 0, 0);
                rz2[i] = __builtin_amdgcn_mfma_f32_16x16x32_bf16(mhi, bihl, rz2[i], 0, 0, 0);
                rz2[i] = __builtin_amdgcn_mfma_f32_16x16x32_bf16(mlo, bihh, rz2[i], 0, 0, 0);
                rz2[i] = __builtin_amdgcn_mfma_f32_16x16x32_bf16(hhi, bhhh, rz2[i], 0, 0, 0);
                rz2[i] = __builtin_amdgcn_mfma_f32_16x16x32_bf16(hhi, bhhl, rz2[i], 0, 0, 0);
                rz2[i] = __builtin_amdgcn_mfma_f32_16x16x32_bf16(hlo, bhhh, rz2[i], 0, 0, 0);
            }
            #pragma unroll
            for (int i = 0; i < 4; ++i) {          // n tiles 8..11
                const int tn = 8 + i;
                short8 bihh = *(const short8*)(ih + tn * 512);
                short8 bihl = *(const short8*)(il + tn * 512);
                short8 bhhh = *(const short8*)(hh + tn * 512);
                short8 bhhl = *(const short8*)(hl + tn * 512);
                niA[i] = __builtin_amdgcn_mfma_f32_16x16x32_bf16(mhi, bihh, niA[i], 0, 0, 0);
                niA[i] = __builtin_amdgcn_mfma_f32_16x16x32_bf16(mhi, bihl, niA[i], 0, 0, 0);
                niA[i] = __builtin_amdgcn_mfma_f32_16x16x32_bf16(mlo, bihh, niA[i], 0, 0, 0);
                nhA[i] = __builtin_amdgcn_mfma_f32_16x16x32_bf16(hhi, bhhh, nhA[i], 0, 0, 0);
                nhA[i] = __builtin_amdgcn_mfma_f32_16x16x32_bf16(hhi, bhhl, nhA[i], 0, 0, 0);
                nhA[i] = __builtin_amdgcn_mfma_f32_16x16x32_bf16(hlo, bhhh, nhA[i], 0, 0, 0);
            }
        }
        #pragma unroll
        for (int rr = 0; rr < 4; ++rr) {
            const int gr = mt * 16 + quad * 4 + rr;
            #pragma unroll
            for (int i = 0; i < 2; ++i) gl[gr][(6 + i) * 16 + col] = rz2[i][rr];
            #pragma unroll
            for (int i = 0; i < 4; ++i) {
                gl[gr][128 + i * 16 + col] = niA[i][rr];
                gl[gr][192 + i * 16 + col] = nhA[i][rr];
            }
        }
    }
    LGKM0(); SBAR(); SCHED0();   // barrier C: gate tiles visible

    // combine: 32 rows x 64 outputs, 8 per thread; one thread per output.
    {
        const int r  = threadIdx.x >> 3;
        const int g0 = (threadIdx.x & 7) * 8;
        const size_t gw = (size_t)(fbase + r) * 64;
        #pragma unroll
        for (int j = 0; j < 8; ++j) {
            const int g = g0 + j;
            float rv = sigm(gl[r][g] + bsum[g]);
            float zv = sigm(gl[r][64 + g] + bsum[64 + g]);
            float nv = tanh_f(gl[r][128 + g] + bih[128 + g]
                              + rv * (gl[r][192 + g] + bhh[128 + g]));
            float ho = fstate[gw + g];
            fstate[gw + g] = (1.f - zv) * nv + zv * ho;
        }
    }
}

// ---------- MFMA GRU: h = GRU(nm, h), bf16 hi/lo, 4 waves x 16 rows ----------
// (var nodes only; nzero=NN re-zeroes nm for next step's f2v atomics.)
__global__ __launch_bounds__(256, 3)
void k_gru_mfma(float* __restrict__ nm,
                const unsigned short* __restrict__ wih_h, const unsigned short* __restrict__ wih_l,
                const unsigned short* __restrict__ whh_h, const unsigned short* __restrict__ whh_l,
                const float* __restrict__ bsum,          // bih+bhh [192]
                const float* __restrict__ bih, const float* __restrict__ bhh,
                float* __restrict__ hst, int count, int nzero)
{
    __shared__ float Hs[64][68];              // 17.4 KB, stride-68 conflict-free
    const int lane = threadIdx.x & 63;
    const int wv   = threadIdx.x >> 6;        // 0..3
    const int quad = lane >> 4;
    const int col  = lane & 15;
    const int base = blockIdx.x * 64;

    float4 am[4], ah[4];
    {
        int ra = base + wv * 16 + col;
        ra = ra < count ? ra : count - 1;
        const float4* pm = (const float4*)(nm + (size_t)ra * 64);
        const float4* ph = (const float4*)(hst + (size_t)ra * 64);
        am[0] = pm[quad * 2];     am[1] = pm[quad * 2 + 1];
        am[2] = pm[8 + quad * 2]; am[3] = pm[8 + quad * 2 + 1];
        ah[0] = ph[quad * 2];     ah[1] = ph[quad * 2 + 1];
        ah[2] = ph[8 + quad * 2]; ah[3] = ph[8 + quad * 2 + 1];
    }
    float bsr[4], bsz[4], bin_[4], bhn[4];
    #pragma unroll
    for (int t = 0; t < 4; ++t) {
        int g = t * 16 + col;
        bsr[t] = bsum[g]; bsz[t] = bsum[64 + g];
        bin_[t] = bih[128 + g]; bhn[t] = bhh[128 + g];
    }
    {
        int rowl = wv * 16 + col;
        *(float4*)(&Hs[rowl][quad * 8])          = ah[0];
        *(float4*)(&Hs[rowl][quad * 8 + 4])      = ah[1];
        *(float4*)(&Hs[rowl][32 + quad * 8])     = ah[2];
        *(float4*)(&Hs[rowl][32 + quad * 8 + 4]) = ah[3];
    }

    f32x4 rz[8], ni[4], nh[4];
    #pragma unroll
    for (int t = 0; t < 8; ++t) rz[t] = (f32x4){0.f, 0.f, 0.f, 0.f};
    #pragma unroll
    for (int t = 0; t < 4; ++t) {
        ni[t] = (f32x4){0.f, 0.f, 0.f, 0.f};
        nh[t] = (f32x4){0.f, 0.f, 0.f, 0.f};
    }

    #pragma unroll
    for (int ck = 0; ck < 2; ++ck) {
        short8 mhi, mlo, hhi, hlo;
        {
            float xv[8];
            f4pair_to8(am[ck * 2], am[ck * 2 + 1], xv);
            split8(xv, mhi, mlo);
            f4pair_to8(ah[ck * 2], ah[ck * 2 + 1], xv);
            split8(xv, hhi, hlo);
        }
        const unsigned short* ih = wih_h + (size_t)(ck * 12) * 512 + lane * 8;
        const unsigned short* il = wih_l + (size_t)(ck * 12) * 512 + lane * 8;
        const unsigned short* hh = whh_h + (size_t)(ck * 12) * 512 + lane * 8;
        const unsigned short* hl = whh_l + (size_t)(ck * 12) * 512 + lane * 8;
        PRIO1();
        #pragma unroll
        for (int tn = 0; tn < 8; ++tn) {
            short8 bihh = *(const short8*)(ih + tn * 512);
            short8 bihl = *(const short8*)(il + tn * 512);
            short8 bhhh = *(const short8*)(hh + tn * 512);
            short8 bhhl = *(const short8*)(hl + tn * 512);
            rz[tn] = __builtin_amdgcn_mfma_f32_16x16x32_bf16(mhi, bihh, rz[tn], 0, 0, 0);
            rz[tn] = __builtin_amdgcn_mfma_f32_16x16x32_bf16(mhi, bihl, rz[tn], 0, 0, 0);
            rz[tn] = __builtin_amdgcn_mfma_f32_16x16x32_bf16(mlo, bihh, rz[tn], 0, 0, 0);
            rz[tn] = __builtin_amdgcn_mfma_f32_16x16x32_bf16(hhi, bhhh, rz[tn], 0, 0, 0);
            rz[tn] = __builtin_amdgcn_mfma_f32_16x16x32_bf16(hhi, bhhl, rz[tn], 0, 0, 0);
            rz[tn] = __builtin_amdgcn_mfma_f32_16x16x32_bf16(hlo, bhhh, rz[tn], 0, 0, 0);
        }
        #pragma unroll
        for (int tn = 8; tn < 12; ++tn) {
            short8 bihh = *(const short8*)(ih + tn * 512);
            short8 bihl = *(const short8*)(il + tn * 512);
            short8 bhhh = *(const short8*)(hh + tn * 512);
            short8 bhhl = *(const short8*)(hl + tn * 512);
            ni[tn - 8] = __builtin_amdgcn_mfma_f32_16x16x32_bf16(mhi, bihh, ni[tn - 8], 0, 0, 0);
            ni[tn - 8] = __builtin_amdgcn_mfma_f32_16x16x32_bf16(mhi, bihl, ni[tn - 8], 0, 0, 0);
            ni[tn - 8] = __builtin_amdgcn_mfma_f32_16x16x32_bf16(mlo, bihh, ni[tn - 8], 0, 0, 0);
            nh[tn - 8] = __builtin_amdgcn_mfma_f32_16x16x32_bf16(hhi, bhhh, nh[tn - 8], 0, 0, 0);
            nh[tn - 8] = __builtin_amdgcn_mfma_f32_16x16x32_bf16(hhi, bhhl, nh[tn - 8], 0, 0, 0);
            nh[tn - 8] = __builtin_amdgcn_mfma_f32_16x16x32_bf16(hlo, bhhh, nh[tn - 8], 0, 0, 0);
        }
        PRIO0();
    }

    #pragma unroll
    for (int rr = 0; rr < 4; ++rr) {
        int rowl = wv * 16 + quad * 4 + rr;
        int grow = base + rowl;
        bool ok = grow < count;
        #pragma unroll
        for (int t = 0; t < 4; ++t) {
            int g = t * 16 + col;
            float rv = sigm(rz[t][rr] + bsr[t]);
            float zv = sigm(rz[4 + t][rr] + bsz[t]);
            float nv = tanh_f(ni[t][rr] + bin_[t] + rv * (nh[t][rr] + bhn[t]));
            if (ok) {
                float ho = Hs[rowl][g];
                hst[(size_t)grow * 64 + g] = (1.f - zv) * nv + zv * ho;
            }
            if (grow < nzero) nm[(size_t)grow * 64 + g] = 0.f;
        }
    }
}

// ---------- readout (unchanged) ----------
__global__ __launch_bounds__(256, 3)
void k_readout(const float* __restrict__ vh,
               const float* __restrict__ w1t, const float* __restrict__ b1,
               const float* __restrict__ w2t, const float* __restrict__ b2,
               const float* __restrict__ w3, const float* __restrict__ b3,
               float* __restrict__ out)
{
    __shared__ float H[HRDIM][64];
    const int lane = threadIdx.x & 63;
    const int wv   = __builtin_amdgcn_readfirstlane(threadIdx.x >> 6);
    const int n0 = blockIdx.x * 64 + lane;
    const int n  = n0 < NN ? n0 : NN - 1;
    const float4* px = (const float4*)(vh + (size_t)n * 64);

    const int j1 = 32 * wv;
    float acc[32];
    #pragma unroll
    for (int j = 0; j < 32; ++j) acc[j] = b1[j1 + j];
    #pragma unroll 4
    for (int q = 0; q < 16; ++q) {
        float4 x4 = px[q];
        const float* wa = w1t + (4 * q + 0) * HRDIM + j1;
        const float* wb = w1t + (4 * q + 1) * HRDIM + j1;
        const float* wc = w1t + (4 * q + 2) * HRDIM + j1;
        const float* wd = w1t + (4 * q + 3) * HRDIM + j1;
        #pragma unroll
        for (int j = 0; j < 32; ++j) {
            acc[j] = fmaf(wa[j], x4.x, acc[j]);
            acc[j] = fmaf(wb[j], x4.y, acc[j]);
            acc[j] = fmaf(wc[j], x4.z, acc[j]);
            acc[j] = fmaf(wd[j], x4.w, acc[j]);
        }
    }
    #pragma unroll
    for (int j = 0; j < 32; ++j) H[j1 + j][lane] = fmaxf(acc[j], 0.f);
    __syncthreads();

    #pragma unroll
    for (int j = 0; j < 32; ++j) acc[j] = b2[j1 + j];
    #pragma unroll 4
    for (int k = 0; k < HRDIM; ++k) {
        float xk = H[k][lane];
        const float* wr = w2t + k * HRDIM + j1;
        #pragma unroll
        for (int j = 0; j < 32; ++j)
            acc[j] = fmaf(wr[j], xk, acc[j]);
    }
    __syncthreads();
    #pragma unroll
    for (int j = 0; j < 32; ++j) H[j1 + j][lane] = fmaxf(acc[j], 0.f);
    __syncthreads();

    if (wv == 0 && n0 < NN) {
        float l0 = b3[0], l1 = b3[1];
        #pragma unroll 8
        for (int k = 0; k < HRDIM; ++k) {
            float hk = H[k][lane];
            l0 = fmaf(w3[k],         hk, l0);
            l1 = fmaf(w3[HRDIM + k], hk, l1);
        }
        float mx = fmaxf(l0, l1);
        float e0 = __expf(l0 - mx), e1 = __expf(l1 - mx);
        float inv = 1.f / (e0 + e1);
        out[2 * n + 0] = e0 * inv;
        out[2 * n + 1] = e1 * inv;
    }
}

// ---------- host ----------
extern "C" void kernel_launch(void* const* d_in, const int* in_sizes, int n_in,
                              void* d_out, int out_size, void* d_ws, size_t ws_size,
                              hipStream_t stream)
{
    float* var_h = (float*)d_ws;
    float* fac_h = var_h + 640000;
    float* nm    = fac_h + 5120000;
    float* ro_t  = nm + 5120000;            // 24,576 f32
    float* bsum  = ro_t + 24576;            // 384 f32 (2 x 192)
    unsigned short* pk = (unsigned short*)(bsum + 384); // 278,528 shorts

    const int*   f2v_row  = (const int*)d_in[0];
    const int*   f2v_col  = (const int*)d_in[1];
    const int*   v2f_row  = (const int*)d_in[2];
    const int*   v2f_col  = (const int*)d_in[3];
    const float* f2v_feat = (const float*)d_in[4];
    const float* v2f_feat = (const float*)d_in[5];
    const float* W[26];
    for (int j = 0; j < 26; ++j) W[j] = (const float*)d_in[6 + j];
    (void)f2v_row; (void)v2f_col;

    TArgs ta;
    float* T[NTR];
    {
        const float* src[NTR] = { W[20], W[22] };
        int R[NTR] = { HRDIM, HRDIM };
        int C[NTR] = { SDIM, HRDIM };
        size_t off = 0;
        for (int t = 0; t < NTR; ++t) {
            ta.src[t] = src[t]; ta.R[t] = R[t]; ta.C[t] = C[t];
            T[t] = ro_t + off; ta.dst[t] = T[t];
            off += (size_t)R[t] * C[t];
        }
    }
    unsigned short* P[12];
    unsigned short* G[8];
    {
        size_t off = 0;
        int esz[3] = { 20480, 16384, 8192 };
        for (int d = 0; d < 2; ++d)
            for (int m = 0; m < 3; ++m) {
                P[d * 6 + m * 2 + 0] = pk + off; off += esz[m];
                P[d * 6 + m * 2 + 1] = pk + off; off += esz[m];
            }
        for (int t = 0; t < 8; ++t) { G[t] = pk + off; off += 12288; }
    }
    PArgs pa;
    {
        const float* src[NPK] = { W[0], W[2], W[4], W[6], W[8], W[10],
                                  W[12], W[13], W[16], W[17] };
        int N[NPK]  = { HMDIM, HMDIM, SDIM,  HMDIM, HMDIM, SDIM,  192, 192, 192, 192 };
        int K[NPK]  = { KIN,   HMDIM, HMDIM, KIN,   HMDIM, HMDIM, SDIM, SDIM, SDIM, SDIM };
        int CK[NPK] = { 5,     4,     4,     5,     4,     4,     2,   2,   2,   2 };
        unsigned short* hi[NPK] = { P[0], P[2], P[4], P[6], P[8], P[10],
                                    G[0], G[2], G[4], G[6] };
        unsigned short* lo[NPK] = { P[1], P[3], P[5], P[7], P[9], P[11],
                                    G[1], G[3], G[5], G[7] };
        for (int t = 0; t < NPK; ++t) {
            pa.src[t] = src[t]; pa.N[t] = N[t]; pa.K[t] = K[t]; pa.CK[t] = CK[t];
            pa.hi[t] = hi[t];   pa.lo[t] = lo[t];
        }
    }
    k_transpose<<<NTR, 256, 0, stream>>>(ta);
    k_pack<<<NPK, 256, 0, stream>>>(pa);
    k_bsum<<<1, 256, 0, stream>>>(W[14], W[15], bsum, W[18], W[19], bsum + 192);
    k_zero<<<512, 256, 0, stream>>>(var_h, 640000 + 5120000 + 5120000);

    for (int s = 0; s < NSTEPS; ++s) {
        // fac -> var messages into nm[node] (atomic scatter); var GRU reads
        // nm and re-zeroes rows [0,NN) for the next step's atomics.
        k_edge_mfma<<<NE / 64, 256, 0, stream>>>(
            fac_h, var_h, f2v_col, f2v_feat,
            P[0], P[1], P[2], P[3], P[4], P[5],
            W[1], W[3], W[5], nm);
        k_gru_mfma<<<(NN + 63) / 64, 256, 0, stream>>>(
            nm, G[0], G[1], G[2], G[3], bsum, W[14], W[15], var_h, NN, NN);
        // var -> fac messages + fac GRU, fused (factor messages stay in LDS;
        // nm untouched in the factor region).
        k_edge_gru_fused<<<NE / 64, 256, 0, stream>>>(
            var_h, fac_h, v2f_row, v2f_feat,
            P[6], P[7], P[8], P[9], P[10], P[11],
            W[7], W[9], W[11],
            G[4], G[5], G[6], G[7], bsum + 192, W[18], W[19]);
    }
    k_readout<<<(NN + 63) / 64, 256, 0, stream>>>(
        var_h, T[0], W[21], T[1], W[23], W[24], W[25],
        (float*)d_out);
}

// Round 14
// 969.608 us; speedup vs baseline: 1.0164x; 1.0164x over previous
//
#include <hip/hip_runtime.h>
#include <hip/hip_bf16.h>

// Problem constants (fixed by reference setup)
#define NN     10000      // variable nodes
#define NF     80000      // factors
#define NE     160000     // directed edges per direction
#define SDIM   64         // state dim
#define HMDIM  128        // hidden (message MLP)
#define HRDIM  128        // hidden (readout)
#define KIN    136        // 2*S + 8
#define NSTEPS 5

static_assert(NE % 64 == 0, "edge grid exact");

typedef __attribute__((ext_vector_type(8))) short short8;   // 8 bf16 = 4 VGPRs
typedef __attribute__((ext_vector_type(4))) float f32x4;    // MFMA C/D

// ---------- helpers ----------
static __device__ __forceinline__ float bf2f(unsigned short u) {
    return __uint_as_float(((unsigned int)u) << 16);
}
// R4: pure fp16 fails absmax; 3-MFMA bf16 hi/lo is the numerics floor.
// R9: direct-global B for the edge MLP is latency-bound; staged-LDS only.
// R12: single-barrier phases + gl stride pad both regressed.
// R13 lesson: the fused kernel's layer-3 staging loop was MISSING its
// trailing barrier since R10 — a latent double-buffer race (STAGE at h3+1
// overwrites the buffer h3's MFMAs read, with no separation). R11 passed by
// timing luck; R13 (same bytes) hit it: absmax 0.1035. R14 adds the
// trailing barrier, matching the f2v kernel's proven layer-3 structure.
static __device__ __forceinline__ unsigned short f2bf(float f) {
    __hip_bfloat16 h = __float2bfloat16(f);
    unsigned short u;
    __builtin_memcpy(&u, &h, 2);
    return u;
}
static __device__ __forceinline__ float sigm(float x) {
    x = fminf(fmaxf(x, -30.f), 30.f);
    return 1.f / (1.f + __expf(-x));
}
static __device__ __forceinline__ float tanh_f(float x) {
    x = fminf(fmaxf(x, -15.f), 15.f);
    float t = __expf(2.f * x);
    return (t - 1.f) / (t + 1.f);
}
// split f32 -> bf16 hi + bf16 lo (x ~= hi + lo, ~16 mantissa bits kept)
static __device__ __forceinline__ void split8(const float* x, short8& hi, short8& lo) {
    #pragma unroll
    for (int i = 0; i < 8; ++i) {
        unsigned short h = f2bf(x[i]);
        hi[i] = (short)h;
        lo[i] = (short)f2bf(x[i] - bf2f(h));
    }
}
static __device__ __forceinline__ void f4pair_to8(float4 a, float4 b, float* xv) {
    xv[0]=a.x; xv[1]=a.y; xv[2]=a.z; xv[3]=a.w;
    xv[4]=b.x; xv[5]=b.y; xv[6]=b.z; xv[7]=b.w;
}
// async global->LDS DMA, 16B per lane, no VGPR round-trip (tracked by vmcnt)
static __device__ __forceinline__ void dma16(const unsigned short* g, unsigned short* l) {
    __builtin_amdgcn_global_load_lds(
        (const __attribute__((address_space(1))) void*)g,
        (__attribute__((address_space(3))) void*)l,
        16, 0, 0);
}

#define LGKM0() asm volatile("s_waitcnt lgkmcnt(0)" ::: "memory")
#define VMC2()  asm volatile("s_waitcnt vmcnt(2)"   ::: "memory")
#define VMC0()  asm volatile("s_waitcnt vmcnt(0)"   ::: "memory")
#define SBAR()  __builtin_amdgcn_s_barrier()
#define SCHED0() __builtin_amdgcn_sched_barrier(0)
#define PRIO1() __builtin_amdgcn_s_setprio(1)
#define PRIO0() __builtin_amdgcn_s_setprio(0)

__global__ void k_zero(float* __restrict__ p, int n) {
    int i = blockIdx.x * blockDim.x + threadIdx.x;
    int stride = gridDim.x * blockDim.x;
    for (; i < n; i += stride) p[i] = 0.f;
}

// ---------- weight transpose for readout (dst[k][j] = src[j][k]) ----------
#define NTR 2
struct TArgs {
    const float* src[NTR];
    float*       dst[NTR];
    int          R[NTR];
    int          C[NTR];
};
__global__ void k_transpose(TArgs a) {
    const int b = blockIdx.x;
    const float* s = a.src[b];
    float* d = a.dst[b];
    const int R = a.R[b], C = a.C[b], n = R * C;
    for (int i = threadIdx.x; i < n; i += blockDim.x) {
        int r = i / C, c = i % C;
        d[c * R + r] = s[i];
    }
}

// ---------- pack weights into B-fragment streams (hi/lo bf16) ----------
#define NPK 10
struct PArgs {
    const float*    src[NPK];
    unsigned short* hi[NPK];
    unsigned short* lo[NPK];
    int             N[NPK], K[NPK], CK[NPK];
};
__global__ void k_pack(PArgs a) {
    const int b = blockIdx.x;
    const float* s = a.src[b];
    unsigned short* ph = a.hi[b];
    unsigned short* pl = a.lo[b];
    const int N = a.N[b], K = a.K[b], CK = a.CK[b];
    const int NT = N >> 4;
    const int total = NT * CK * 512;
    for (int i = threadIdx.x; i < total; i += blockDim.x) {
        int j    = i & 7;
        int ln   = (i >> 3) & 63;
        int tile = i >> 9;
        int tn   = tile % NT;
        int ck   = tile / NT;
        int k = ck * 32 + ((ln >> 4) * 8) + j;
        int n = tn * 16 + (ln & 15);
        float f = (k < K) ? s[n * K + k] : 0.f;
        unsigned short h = f2bf(f);
        ph[i] = h;
        pl[i] = f2bf(f - bf2f(h));
    }
}

// bias sums for GRU r/z gates: o[j] = bih[j] + bhh[j], j in [0,192)
__global__ void k_bsum(const float* bih0, const float* bhh0, float* o0,
                       const float* bih1, const float* bhh1, float* o1) {
    int i = threadIdx.x;
    if (i < 192) { o0[i] = bih0[i] + bhh0[i]; o1[i] = bih1[i] + bhh1[i]; }
}

// ---- half-phase B staging: 4KB hi + 4KB lo per half-phase, dbuf 16KB ----
#define STAGE(buf, sh, sl) do {                                            \
    const int u0_ = wv * 2;                                                \
    _Pragma("unroll")                                                      \
    for (int k_ = 0; k_ < 2; ++k_) {                                       \
        const int u_ = u0_ + k_;                                           \
        const unsigned short* s_ = (u_ < 4 ? (sh) : (sl)) + (u_ & 3) * 512;\
        unsigned short* d_ = (u_ < 4 ? &BH[buf][0] : &BL[buf][0]) + (u_ & 3) * 512; \
        dma16(s_ + lane * 8, d_);                                          \
    }                                                                      \
} while (0)

// ---------- f2v MFMA edge MLP + atomic scatter (R8 structure, 71.5us) ----------
__global__ __launch_bounds__(256, 3)
void k_edge_mfma(const float* __restrict__ hrow, const float* __restrict__ hcol,
                 const int* __restrict__ cols,
                 const float* __restrict__ feat,
                 const unsigned short* __restrict__ w1h, const unsigned short* __restrict__ w1l,
                 const unsigned short* __restrict__ w2h, const unsigned short* __restrict__ w2l,
                 const unsigned short* __restrict__ w3h, const unsigned short* __restrict__ w3l,
                 const float* __restrict__ b1, const float* __restrict__ b2,
                 const float* __restrict__ b3,
                 float* __restrict__ nm)
{
    __shared__ __align__(16) unsigned short Hhi[64][136];   // 17.0 KB
    __shared__ __align__(16) unsigned short Hlo[64][136];   // 17.0 KB
    __shared__ __align__(16) unsigned short BH[2][2048];    // 8 KB (dbuf hi)
    __shared__ __align__(16) unsigned short BL[2][2048];    // 8 KB (dbuf lo)
    const int lane = threadIdx.x & 63;
    const int wv   = threadIdx.x >> 6;        // 0..3
    const int quad = lane >> 4;               // 0..3
    const int col  = lane & 15;

    const int e0 = blockIdx.x * 64 + wv * 16 + col;
    const int r0 = e0 >> 1;                   // f2v rows = fidx = e/2
    const int c0 = cols[e0];

    float4 gR[4], gC[4], gFr, gFc;
    {
        const float4* pr = (const float4*)(hrow + (size_t)r0 * 64);
        const float4* pc = (const float4*)(hcol + (size_t)c0 * 64);
        gR[0] = pr[quad * 2];     gR[1] = pr[quad * 2 + 1];
        gR[2] = pr[8 + quad * 2]; gR[3] = pr[8 + quad * 2 + 1];
        gC[0] = pc[quad * 2];     gC[1] = pc[quad * 2 + 1];
        gC[2] = pc[8 + quad * 2]; gC[3] = pc[8 + quad * 2 + 1];
        gFr = *(const float4*)(feat + (size_t)r0 * 4);
        gFc = *(const float4*)(feat + (size_t)c0 * 4);
    }
    int cc[4];
    #pragma unroll
    for (int rr = 0; rr < 4; ++rr)
        cc[rr] = cols[blockIdx.x * 64 + wv * 16 + quad * 4 + rr];

    float b1v[8], b2v[8], b3v[4];
    #pragma unroll
    for (int t = 0; t < 8; ++t) { b1v[t] = b1[t * 16 + col]; b2v[t] = b2[t * 16 + col]; }
    #pragma unroll
    for (int t = 0; t < 4; ++t) b3v[t] = b3[t * 16 + col];

    VMC0(); SCHED0();
    STAGE(0, w1h, w1l);

    f32x4 acc[8];
    #pragma unroll
    for (int t = 0; t < 8; ++t) acc[t] = (f32x4){0.f, 0.f, 0.f, 0.f};

    short8 ahi, alo;
    #pragma unroll
    for (int hp = 0; hp < 10; ++hp) {
        {
            const unsigned short* nh; const unsigned short* nl;
            if (hp < 9) { nh = w1h + (hp + 1) * 2048; nl = w1l + (hp + 1) * 2048; }
            else        { nh = w2h;                   nl = w2l; }
            STAGE((hp + 1) & 1, nh, nl);
        }
        if ((hp & 1) == 0) {
            const int ck = hp >> 1;
            float xv[8];
            if (ck < 2)      f4pair_to8(gR[ck * 2], gR[ck * 2 + 1], xv);
            else if (ck < 4) f4pair_to8(gC[(ck - 2) * 2], gC[(ck - 2) * 2 + 1], xv);
            else if (quad == 0) f4pair_to8(gFr, gFc, xv);
            else {
                #pragma unroll
                for (int i = 0; i < 8; ++i) xv[i] = 0.f;
            }
            split8(xv, ahi, alo);
        }
        VMC2(); LGKM0(); SBAR(); SCHED0();
        {
            const unsigned short* bh = &BH[hp & 1][0];
            const unsigned short* bl = &BL[hp & 1][0];
            #pragma unroll
            for (int t = 0; t < 4; ++t) {
                const int tn = (hp & 1) * 4 + t;
                short8 bhi = *(const short8*)(bh + t * 512 + lane * 8);
                short8 blo = *(const short8*)(bl + t * 512 + lane * 8);
                acc[tn] = __builtin_amdgcn_mfma_f32_16x16x32_bf16(ahi, bhi, acc[tn], 0, 0, 0);
                acc[tn] = __builtin_amdgcn_mfma_f32_16x16x32_bf16(ahi, blo, acc[tn], 0, 0, 0);
                acc[tn] = __builtin_amdgcn_mfma_f32_16x16x32_bf16(alo, bhi, acc[tn], 0, 0, 0);
            }
        }
        LGKM0(); SBAR(); SCHED0();
    }
    #pragma unroll
    for (int tn = 0; tn < 8; ++tn)
        #pragma unroll
        for (int rr = 0; rr < 4; ++rr) {
            float v = fmaxf(acc[tn][rr] + b1v[tn], 0.f);
            int m = wv * 16 + quad * 4 + rr;
            unsigned short h = f2bf(v);
            Hhi[m][tn * 16 + col] = h;
            Hlo[m][tn * 16 + col] = f2bf(v - bf2f(h));
        }

    #pragma unroll
    for (int t = 0; t < 8; ++t) acc[t] = (f32x4){0.f, 0.f, 0.f, 0.f};
    const int m0 = wv * 16 + col;
    #pragma unroll
    for (int h2 = 0; h2 < 8; ++h2) {
        const int hp = 10 + h2;
        {
            const unsigned short* nh; const unsigned short* nl;
            if (h2 < 7) { nh = w2h + (h2 + 1) * 2048; nl = w2l + (h2 + 1) * 2048; }
            else        { nh = w3h;                   nl = w3l; }
            STAGE((hp + 1) & 1, nh, nl);
        }
        if ((h2 & 1) == 0) {
            const int ck = h2 >> 1;
            ahi = *(const short8*)(&Hhi[m0][ck * 32 + quad * 8]);
            alo = *(const short8*)(&Hlo[m0][ck * 32 + quad * 8]);
        }
        VMC2(); LGKM0(); SBAR(); SCHED0();
        {
            const unsigned short* bh = &BH[hp & 1][0];
            const unsigned short* bl = &BL[hp & 1][0];
            #pragma unroll
            for (int t = 0; t < 4; ++t) {
                const int tn = (h2 & 1) * 4 + t;
                short8 bhi = *(const short8*)(bh + t * 512 + lane * 8);
                short8 blo = *(const short8*)(bl + t * 512 + lane * 8);
                acc[tn] = __builtin_amdgcn_mfma_f32_16x16x32_bf16(ahi, bhi, acc[tn], 0, 0, 0);
                acc[tn] = __builtin_amdgcn_mfma_f32_16x16x32_bf16(ahi, blo, acc[tn], 0, 0, 0);
                acc[tn] = __builtin_amdgcn_mfma_f32_16x16x32_bf16(alo, bhi, acc[tn], 0, 0, 0);
            }
        }
        LGKM0(); SBAR(); SCHED0();
    }
    #pragma unroll
    for (int tn = 0; tn < 8; ++tn)
        #pragma unroll
        for (int rr = 0; rr < 4; ++rr) {
            float v = fmaxf(acc[tn][rr] + b2v[tn], 0.f);
            int m = wv * 16 + quad * 4 + rr;
            unsigned short h = f2bf(v);
            Hhi[m][tn * 16 + col] = h;
            Hlo[m][tn * 16 + col] = f2bf(v - bf2f(h));
        }

    f32x4 a3[4];
    #pragma unroll
    for (int t = 0; t < 4; ++t) a3[t] = (f32x4){0.f, 0.f, 0.f, 0.f};
    #pragma unroll
    for (int h3 = 0; h3 < 4; ++h3) {
        const int hp = 18 + h3;
        if (h3 < 3) STAGE((hp + 1) & 1, w3h + (h3 + 1) * 2048, w3l + (h3 + 1) * 2048);
        short8 a3h = *(const short8*)(&Hhi[m0][h3 * 32 + quad * 8]);
        short8 a3l = *(const short8*)(&Hlo[m0][h3 * 32 + quad * 8]);
        if (h3 < 3) { VMC2(); } else { VMC0(); }
        LGKM0(); SBAR(); SCHED0();
        {
            const unsigned short* bh = &BH[hp & 1][0];
            const unsigned short* bl = &BL[hp & 1][0];
            #pragma unroll
            for (int t = 0; t < 4; ++t) {
                short8 bhi = *(const short8*)(bh + t * 512 + lane * 8);
                short8 blo = *(const short8*)(bl + t * 512 + lane * 8);
                a3[t] = __builtin_amdgcn_mfma_f32_16x16x32_bf16(a3h, bhi, a3[t], 0, 0, 0);
                a3[t] = __builtin_amdgcn_mfma_f32_16x16x32_bf16(a3h, blo, a3[t], 0, 0, 0);
                a3[t] = __builtin_amdgcn_mfma_f32_16x16x32_bf16(a3l, bhi, a3[t], 0, 0, 0);
            }
        }
        if (h3 < 3) { LGKM0(); SBAR(); SCHED0(); }
    }

    #pragma unroll
    for (int tn = 0; tn < 4; ++tn) {
        float bias = b3v[tn];
        #pragma unroll
        for (int rr = 0; rr < 4; ++rr)
            atomicAdd(&nm[(size_t)cc[rr] * 64 + tn * 16 + col], a3[tn][rr] + bias);
    }
}

// ---------- FUSED v2f edge MLP + fac GRU ----------
// R14: adds the trailing barrier in the layer-3 staging loop (matching the
// f2v kernel) — fixes the latent double-buffer race present since R10.
__global__ __launch_bounds__(256, 3)
void k_edge_gru_fused(const float* __restrict__ hrow, float* fstate,
                      const int* __restrict__ rows,
                      const float* __restrict__ feat,
                      const unsigned short* __restrict__ w1h, const unsigned short* __restrict__ w1l,
                      const unsigned short* __restrict__ w2h, const unsigned short* __restrict__ w2l,
                      const unsigned short* __restrict__ w3h, const unsigned short* __restrict__ w3l,
                      const float* __restrict__ b1, const float* __restrict__ b2,
                      const float* __restrict__ b3,
                      const unsigned short* __restrict__ gih_h, const unsigned short* __restrict__ gih_l,
                      const unsigned short* __restrict__ ghh_h, const unsigned short* __restrict__ ghh_l,
                      const float* __restrict__ bsum, const float* __restrict__ bih,
                      const float* __restrict__ bhh)
{
    // 51200B arena. Phase-1: Hhi|Hlo|BH|BL. Phase-2 overlays (behind
    // barrier A): nmL = [0,8704) float[32][68]; gl = [8704,41984) float[32][260]
    __shared__ __align__(16) unsigned char SM[51200];
    unsigned short (*Hhi)[136] = (unsigned short(*)[136])(SM);
    unsigned short (*Hlo)[136] = (unsigned short(*)[136])(SM + 17408);
    unsigned short (*BH)[2048] = (unsigned short(*)[2048])(SM + 34816);
    unsigned short (*BL)[2048] = (unsigned short(*)[2048])(SM + 43008);
    float (*nmL)[68]  = (float(*)[68])(SM);
    float (*gl)[260]  = (float(*)[260])(SM + 8704);

    const int lane = threadIdx.x & 63;
    const int wv   = threadIdx.x >> 6;        // 0..3
    const int quad = lane >> 4;               // 0..3
    const int col  = lane & 15;

    const int e0 = blockIdx.x * 64 + wv * 16 + col;
    const int r0 = rows[e0];                  // variable endpoint
    const int c0 = e0 >> 1;                   // v2f cols = fidx = e/2

    float4 gR[4], gC[4], gFr, gFc;
    {
        const float4* pr = (const float4*)(hrow + (size_t)r0 * 64);
        const float4* pc = (const float4*)(fstate + (size_t)c0 * 64);
        gR[0] = pr[quad * 2];     gR[1] = pr[quad * 2 + 1];
        gR[2] = pr[8 + quad * 2]; gR[3] = pr[8 + quad * 2 + 1];
        gC[0] = pc[quad * 2];     gC[1] = pc[quad * 2 + 1];
        gC[2] = pc[8 + quad * 2]; gC[3] = pc[8 + quad * 2 + 1];
        gFr = *(const float4*)(feat + (size_t)r0 * 4);
        gFc = *(const float4*)(feat + (size_t)c0 * 4);
    }
    float b1v[8], b2v[8], b3v[4];
    #pragma unroll
    for (int t = 0; t < 8; ++t) { b1v[t] = b1[t * 16 + col]; b2v[t] = b2[t * 16 + col]; }
    #pragma unroll
    for (int t = 0; t < 4; ++t) b3v[t] = b3[t * 16 + col];

    VMC0(); SCHED0();
    STAGE(0, w1h, w1l);

    f32x4 acc[8];
    #pragma unroll
    for (int t = 0; t < 8; ++t) acc[t] = (f32x4){0.f, 0.f, 0.f, 0.f};

    short8 ahi, alo;
    #pragma unroll
    for (int hp = 0; hp < 10; ++hp) {
        {
            const unsigned short* nh; const unsigned short* nl;
            if (hp < 9) { nh = w1h + (hp + 1) * 2048; nl = w1l + (hp + 1) * 2048; }
            else        { nh = w2h;                   nl = w2l; }
            STAGE((hp + 1) & 1, nh, nl);
        }
        if ((hp & 1) == 0) {
            const int ck = hp >> 1;
            float xv[8];
            if (ck < 2)      f4pair_to8(gR[ck * 2], gR[ck * 2 + 1], xv);
            else if (ck < 4) f4pair_to8(gC[(ck - 2) * 2], gC[(ck - 2) * 2 + 1], xv);
            else if (quad == 0) f4pair_to8(gFr, gFc, xv);
            else {
                #pragma unroll
                for (int i = 0; i < 8; ++i) xv[i] = 0.f;
            }
            split8(xv, ahi, alo);
        }
        VMC2(); LGKM0(); SBAR(); SCHED0();
        {
            const unsigned short* bh = &BH[hp & 1][0];
            const unsigned short* bl = &BL[hp & 1][0];
            #pragma unroll
            for (int t = 0; t < 4; ++t) {
                const int tn = (hp & 1) * 4 + t;
                short8 bhi = *(const short8*)(bh + t * 512 + lane * 8);
                short8 blo = *(const short8*)(bl + t * 512 + lane * 8);
                acc[tn] = __builtin_amdgcn_mfma_f32_16x16x32_bf16(ahi, bhi, acc[tn], 0, 0, 0);
                acc[tn] = __builtin_amdgcn_mfma_f32_16x16x32_bf16(ahi, blo, acc[tn], 0, 0, 0);
                acc[tn] = __builtin_amdgcn_mfma_f32_16x16x32_bf16(alo, bhi, acc[tn], 0, 0, 0);
            }
        }
        LGKM0(); SBAR(); SCHED0();
    }
    #pragma unroll
    for (int tn = 0; tn < 8; ++tn)
        #pragma unroll
        for (int rr = 0; rr < 4; ++rr) {
            float v = fmaxf(acc[tn][rr] + b1v[tn], 0.f);
            int m = wv * 16 + quad * 4 + rr;
            unsigned short h = f2bf(v);
            Hhi[m][tn * 16 + col] = h;
            Hlo[m][tn * 16 + col] = f2bf(v - bf2f(h));
        }

    #pragma unroll
    for (int t = 0; t < 8; ++t) acc[t] = (f32x4){0.f, 0.f, 0.f, 0.f};
    const int m0 = wv * 16 + col;
    #pragma unroll
    for (int h2 = 0; h2 < 8; ++h2) {
        const int hp = 10 + h2;
        {
            const unsigned short* nh; const unsigned short* nl;
            if (h2 < 7) { nh = w2h + (h2 + 1) * 2048; nl = w2l + (h2 + 1) * 2048; }
            else        { nh = w3h;                   nl = w3l; }
            STAGE((hp + 1) & 1, nh, nl);
        }
        if ((h2 & 1) == 0) {
            const int ck = h2 >> 1;
            ahi = *(const short8*)(&Hhi[m0][ck * 32 + quad * 8]);
            alo = *(const short8*)(&Hlo[m0][ck * 32 + quad * 8]);
        }
        VMC2(); LGKM0(); SBAR(); SCHED0();
        {
            const unsigned short* bh = &BH[hp & 1][0];
            const unsigned short* bl = &BL[hp & 1][0];
            #pragma unroll
            for (int t = 0; t < 4; ++t) {
                const int tn = (h2 & 1) * 4 + t;
                short8 bhi = *(const short8*)(bh + t * 512 + lane * 8);
                short8 blo = *(const short8*)(bl + t * 512 + lane * 8);
                acc[tn] = __builtin_amdgcn_mfma_f32_16x16x32_bf16(ahi, bhi, acc[tn], 0, 0, 0);
                acc[tn] = __builtin_amdgcn_mfma_f32_16x16x32_bf16(ahi, blo, acc[tn], 0, 0, 0);
                acc[tn] = __builtin_amdgcn_mfma_f32_16x16x32_bf16(alo, bhi, acc[tn], 0, 0, 0);
            }
        }
        LGKM0(); SBAR(); SCHED0();
    }
    #pragma unroll
    for (int tn = 0; tn < 8; ++tn)
        #pragma unroll
        for (int rr = 0; rr < 4; ++rr) {
            float v = fmaxf(acc[tn][rr] + b2v[tn], 0.f);
            int m = wv * 16 + quad * 4 + rr;
            unsigned short h = f2bf(v);
            Hhi[m][tn * 16 + col] = h;
            Hlo[m][tn * 16 + col] = f2bf(v - bf2f(h));
        }

    f32x4 a3[4];
    #pragma unroll
    for (int t = 0; t < 4; ++t) a3[t] = (f32x4){0.f, 0.f, 0.f, 0.f};
    #pragma unroll
    for (int h3 = 0; h3 < 4; ++h3) {
        const int hp = 18 + h3;
        if (h3 < 3) STAGE((hp + 1) & 1, w3h + (h3 + 1) * 2048, w3l + (h3 + 1) * 2048);
        short8 a3h = *(const short8*)(&Hhi[m0][h3 * 32 + quad * 8]);
        short8 a3l = *(const short8*)(&Hlo[m0][h3 * 32 + quad * 8]);
        if (h3 < 3) { VMC2(); } else { VMC0(); }
        LGKM0(); SBAR(); SCHED0();
        {
            const unsigned short* bh = &BH[hp & 1][0];
            const unsigned short* bl = &BL[hp & 1][0];
            #pragma unroll
            for (int t = 0; t < 4; ++t) {
                short8 bhi = *(const short8*)(bh + t * 512 + lane * 8);
                short8 blo = *(const short8*)(bl + t * 512 + lane * 8);
                a3[t] = __builtin_amdgcn_mfma_f32_16x16x32_bf16(a3h, bhi, a3[t], 0, 0, 0);
                a3[t] = __builtin_amdgcn_mfma_f32_16x16x32_bf16(a3h, blo, a3[t], 0, 0, 0);
                a3[t] = __builtin_amdgcn_mfma_f32_16x16x32_bf16(a3l, bhi, a3[t], 0, 0, 0);
            }
        }
        // R14 FIX: trailing barrier (race: next iteration's STAGE overwrites
        // the buffer this iteration's MFMAs read; f2v always had this).
        if (h3 < 3) { LGKM0(); SBAR(); SCHED0(); }
    }

    // ---- barrier A: every wave done with H/B reads -> overlays safe
    LGKM0(); SBAR(); SCHED0();

    // pairsum -> nmL (factor message tile, rows = local factor 0..31)
    {
        int lf0 = wv * 8 + quad * 2;
        #pragma unroll
        for (int tn = 0; tn < 4; ++tn) {
            float b2x = 2.f * b3v[tn];
            nmL[lf0][tn * 16 + col]     = a3[tn][0] + a3[tn][1] + b2x;
            nmL[lf0 + 1][tn * 16 + col] = a3[tn][2] + a3[tn][3] + b2x;
        }
    }
    LGKM0(); SBAR(); SCHED0();   // barrier B: nmL visible to all waves

    // ---- fused fac GRU: 32 factors, wave = (Mhalf mt, Nhalf half) ----
    const int fbase = blockIdx.x * 32;
    const int mt    = wv >> 1;             // 16-row M-tile
    const int half  = wv & 1;              // gate-tile half (6 of 12)
    const int hrow0 = fbase + mt * 16 + col;

    if (half == 0) {
        f32x4 rz6[6];
        #pragma unroll
        for (int i = 0; i < 6; ++i) rz6[i] = (f32x4){0.f, 0.f, 0.f, 0.f};
        #pragma unroll
        for (int ck = 0; ck < 2; ++ck) {
            short8 mhi, mlo, hhi, hlo;
            {
                float xv[8];
                *(float4*)&xv[0] = *(const float4*)(&nmL[mt * 16 + col][ck * 32 + quad * 8]);
                *(float4*)&xv[4] = *(const float4*)(&nmL[mt * 16 + col][ck * 32 + quad * 8 + 4]);
                split8(xv, mhi, mlo);
                const float* hp_ = fstate + (size_t)hrow0 * 64 + ck * 32 + quad * 8;
                *(float4*)&xv[0] = *(const float4*)(hp_);
                *(float4*)&xv[4] = *(const float4*)(hp_ + 4);
                split8(xv, hhi, hlo);
            }
            const unsigned short* ih = gih_h + (size_t)(ck * 12) * 512 + lane * 8;
            const unsigned short* il = gih_l + (size_t)(ck * 12) * 512 + lane * 8;
            const unsigned short* hh = ghh_h + (size_t)(ck * 12) * 512 + lane * 8;
            const unsigned short* hl = ghh_l + (size_t)(ck * 12) * 512 + lane * 8;
            #pragma unroll
            for (int i = 0; i < 6; ++i) {
                short8 bihh = *(const short8*)(ih + i * 512);
                short8 bihl = *(const short8*)(il + i * 512);
                short8 bhhh = *(const short8*)(hh + i * 512);
                short8 bhhl = *(const short8*)(hl + i * 512);
                rz6[i] = __builtin_amdgcn_mfma_f32_16x16x32_bf16(mhi, bihh, rz6[i], 0, 0, 0);
                rz6[i] = __builtin_amdgcn_mfma_f32_16x16x32_bf16(mhi, bihl, rz6[i], 0, 0, 0);
                rz6[i] = __builtin_amdgcn_mfma_f32_16x16x32_bf16(mlo, bihh, rz6[i], 0, 0, 0);
                rz6[i] = __builtin_amdgcn_mfma_f32_16x16x32_bf16(hhi, bhhh, rz6[i], 0, 0, 0);
                rz6[i] = __builtin_amdgcn_mfma_f32_16x16x32_bf16(hhi, bhhl, rz6[i], 0, 0, 0);
                rz6[i] = __builtin_amdgcn_mfma_f32_16x16x32_bf16(hlo, bhhh, rz6[i], 0, 0, 0);
            }
        }
        #pragma unroll
        for (int i = 0; i < 6; ++i)
            #pragma unroll
            for (int rr = 0; rr < 4; ++rr)
                gl[mt * 16 + quad * 4 + rr][i * 16 + col] = rz6[i][rr];
    } else {
        f32x4 rz2[2], niA[4], nhA[4];
        #pragma unroll
        for (int i = 0; i < 2; ++i) rz2[i] = (f32x4){0.f, 0.f, 0.f, 0.f};
        #pragma unroll
        for (int i = 0; i < 4; ++i) {
            niA[i] = (f32x4){0.f, 0.f, 0.f, 0.f};
            nhA[i] = (f32x4){0.f, 0.f, 0.f, 0.f};
        }
        #pragma unroll
        for (int ck = 0; ck < 2; ++ck) {
            short8 mhi, mlo, hhi, hlo;
            {
                float xv[8];
                *(float4*)&xv[0] = *(const float4*)(&nmL[mt * 16 + col][ck * 32 + quad * 8]);
                *(float4*)&xv[4] = *(const float4*)(&nmL[mt * 16 + col][ck * 32 + quad * 8 + 4]);
                split8(xv, mhi, mlo);
                const float* hp_ = fstate + (size_t)hrow0 * 64 + ck * 32 + quad * 8;
                *(float4*)&xv[0] = *(const float4*)(hp_);
                *(float4*)&xv[4] = *(const float4*)(hp_ + 4);
                split8(xv, hhi, hlo);
            }
            const unsigned short* ih = gih_h + (size_t)(ck * 12) * 512 + lane * 8;
            const unsigned short* il = gih_l + (size_t)(ck * 12) * 512 + lane * 8;
            const unsigned short* hh = ghh_h + (size_t)(ck * 12) * 512 + lane * 8;
            const unsigned short* hl = ghh_l + (size_t)(ck * 12) * 512 + lane * 8;
            #pragma unroll
            for (int i = 0; i < 2; ++i) {          // rz tiles 6,7
                const int tn = 6 + i;
                short8 bihh = *(const short8*)(ih + tn * 512);
                short8 bihl = *(const short8*)(il + tn * 512);
                short8 bhhh = *(const short8*)(hh + tn * 512);
                short8 bhhl = *(const short8*)(hl + tn * 512);
                rz2[i] = __builtin_amdgcn_mfma_f32_16x16x32_bf16(mhi, bihh, rz2[i], 0, 0, 0);
                rz2[i] = __builtin_amdgcn_mfma_f32_16x16x32_bf16(mhi, bihl, rz2[i], 0, 0, 0);
                rz2[i] = __builtin_amdgcn_mfma_f32_16x16x32_bf16(mlo, bihh, rz2[i], 0, 0, 0);
                rz2[i] = __builtin_amdgcn_mfma_f32_16x16x32_bf16(hhi, bhhh, rz2[i], 0, 0, 0);
                rz2[i] = __builtin_amdgcn_mfma_f32_16x16x32_bf16(hhi, bhhl, rz2[i], 0, 0, 0);
                rz2[i] = __builtin_amdgcn_mfma_f32_16x16x32_bf16(hlo, bhhh, rz2[i], 0, 0, 0);
            }
            #pragma unroll
            for (int i = 0; i < 4; ++i) {          // n tiles 8..11
                const int tn = 8 + i;
                short8 bihh = *(const short8*)(ih + tn * 512);
                short8 bihl = *(const short8*)(il + tn * 512);
                short8 bhhh = *(const short8*)(hh + tn * 512);
                short8 bhhl = *(const short8*)(hl + tn * 512);
                niA[i] = __builtin_amdgcn_mfma_f32_16x16x32_bf16(mhi, bihh, niA[i], 0, 0, 0);
                niA[i] = __builtin_amdgcn_mfma_f32_16x16x32_bf16(mhi, bihl, niA[i], 0, 0, 0);
                niA[i] = __builtin_amdgcn_mfma_f32_16x16x32_bf16(mlo, bihh, niA[i], 0, 0, 0);
                nhA[i] = __builtin_amdgcn_mfma_f32_16x16x32_bf16(hhi, bhhh, nhA[i], 0, 0, 0);
                nhA[i] = __builtin_amdgcn_mfma_f32_16x16x32_bf16(hhi, bhhl, nhA[i], 0, 0, 0);
                nhA[i] = __builtin_amdgcn_mfma_f32_16x16x32_bf16(hlo, bhhh, nhA[i], 0, 0, 0);
            }
        }
        #pragma unroll
        for (int rr = 0; rr < 4; ++rr) {
            const int gr = mt * 16 + quad * 4 + rr;
            #pragma unroll
            for (int i = 0; i < 2; ++i) gl[gr][(6 + i) * 16 + col] = rz2[i][rr];
            #pragma unroll
            for (int i = 0; i < 4; ++i) {
                gl[gr][128 + i * 16 + col] = niA[i][rr];
                gl[gr][192 + i * 16 + col] = nhA[i][rr];
            }
        }
    }
    LGKM0(); SBAR(); SCHED0();   // barrier C: gate tiles visible

    // combine: 32 rows x 64 outputs, 8 per thread; one thread per output.
    {
        const int r  = threadIdx.x >> 3;
        const int g0 = (threadIdx.x & 7) * 8;
        const size_t gw = (size_t)(fbase + r) * 64;
        #pragma unroll
        for (int j = 0; j < 8; ++j) {
            const int g = g0 + j;
            float rv = sigm(gl[r][g] + bsum[g]);
            float zv = sigm(gl[r][64 + g] + bsum[64 + g]);
            float nv = tanh_f(gl[r][128 + g] + bih[128 + g]
                              + rv * (gl[r][192 + g] + bhh[128 + g]));
            float ho = fstate[gw + g];
            fstate[gw + g] = (1.f - zv) * nv + zv * ho;
        }
    }
}

// ---------- MFMA GRU: h = GRU(nm, h), bf16 hi/lo, 4 waves x 16 rows ----------
// (var nodes only; nzero=NN re-zeroes nm for next step's f2v atomics.)
__global__ __launch_bounds__(256, 3)
void k_gru_mfma(float* __restrict__ nm,
                const unsigned short* __restrict__ wih_h, const unsigned short* __restrict__ wih_l,
                const unsigned short* __restrict__ whh_h, const unsigned short* __restrict__ whh_l,
                const float* __restrict__ bsum,          // bih+bhh [192]
                const float* __restrict__ bih, const float* __restrict__ bhh,
                float* __restrict__ hst, int count, int nzero)
{
    __shared__ float Hs[64][68];              // 17.4 KB, stride-68 conflict-free
    const int lane = threadIdx.x & 63;
    const int wv   = threadIdx.x >> 6;        // 0..3
    const int quad = lane >> 4;
    const int col  = lane & 15;
    const int base = blockIdx.x * 64;

    float4 am[4], ah[4];
    {
        int ra = base + wv * 16 + col;
        ra = ra < count ? ra : count - 1;
        const float4* pm = (const float4*)(nm + (size_t)ra * 64);
        const float4* ph = (const float4*)(hst + (size_t)ra * 64);
        am[0] = pm[quad * 2];     am[1] = pm[quad * 2 + 1];
        am[2] = pm[8 + quad * 2]; am[3] = pm[8 + quad * 2 + 1];
        ah[0] = ph[quad * 2];     ah[1] = ph[quad * 2 + 1];
        ah[2] = ph[8 + quad * 2]; ah[3] = ph[8 + quad * 2 + 1];
    }
    float bsr[4], bsz[4], bin_[4], bhn[4];
    #pragma unroll
    for (int t = 0; t < 4; ++t) {
        int g = t * 16 + col;
        bsr[t] = bsum[g]; bsz[t] = bsum[64 + g];
        bin_[t] = bih[128 + g]; bhn[t] = bhh[128 + g];
    }
    {
        int rowl = wv * 16 + col;
        *(float4*)(&Hs[rowl][quad * 8])          = ah[0];
        *(float4*)(&Hs[rowl][quad * 8 + 4])      = ah[1];
        *(float4*)(&Hs[rowl][32 + quad * 8])     = ah[2];
        *(float4*)(&Hs[rowl][32 + quad * 8 + 4]) = ah[3];
    }

    f32x4 rz[8], ni[4], nh[4];
    #pragma unroll
    for (int t = 0; t < 8; ++t) rz[t] = (f32x4){0.f, 0.f, 0.f, 0.f};
    #pragma unroll
    for (int t = 0; t < 4; ++t) {
        ni[t] = (f32x4){0.f, 0.f, 0.f, 0.f};
        nh[t] = (f32x4){0.f, 0.f, 0.f, 0.f};
    }

    #pragma unroll
    for (int ck = 0; ck < 2; ++ck) {
        short8 mhi, mlo, hhi, hlo;
        {
            float xv[8];
            f4pair_to8(am[ck * 2], am[ck * 2 + 1], xv);
            split8(xv, mhi, mlo);
            f4pair_to8(ah[ck * 2], ah[ck * 2 + 1], xv);
            split8(xv, hhi, hlo);
        }
        const unsigned short* ih = wih_h + (size_t)(ck * 12) * 512 + lane * 8;
        const unsigned short* il = wih_l + (size_t)(ck * 12) * 512 + lane * 8;
        const unsigned short* hh = whh_h + (size_t)(ck * 12) * 512 + lane * 8;
        const unsigned short* hl = whh_l + (size_t)(ck * 12) * 512 + lane * 8;
        PRIO1();
        #pragma unroll
        for (int tn = 0; tn < 8; ++tn) {
            short8 bihh = *(const short8*)(ih + tn * 512);
            short8 bihl = *(const short8*)(il + tn * 512);
            short8 bhhh = *(const short8*)(hh + tn * 512);
            short8 bhhl = *(const short8*)(hl + tn * 512);
            rz[tn] = __builtin_amdgcn_mfma_f32_16x16x32_bf16(mhi, bihh, rz[tn], 0, 0, 0);
            rz[tn] = __builtin_amdgcn_mfma_f32_16x16x32_bf16(mhi, bihl, rz[tn], 0, 0, 0);
            rz[tn] = __builtin_amdgcn_mfma_f32_16x16x32_bf16(mlo, bihh, rz[tn], 0, 0, 0);
            rz[tn] = __builtin_amdgcn_mfma_f32_16x16x32_bf16(hhi, bhhh, rz[tn], 0, 0, 0);
            rz[tn] = __builtin_amdgcn_mfma_f32_16x16x32_bf16(hhi, bhhl, rz[tn], 0, 0, 0);
            rz[tn] = __builtin_amdgcn_mfma_f32_16x16x32_bf16(hlo, bhhh, rz[tn], 0, 0, 0);
        }
        #pragma unroll
        for (int tn = 8; tn < 12; ++tn) {
            short8 bihh = *(const short8*)(ih + tn * 512);
            short8 bihl = *(const short8*)(il + tn * 512);
            short8 bhhh = *(const short8*)(hh + tn * 512);
            short8 bhhl = *(const short8*)(hl + tn * 512);
            ni[tn - 8] = __builtin_amdgcn_mfma_f32_16x16x32_bf16(mhi, bihh, ni[tn - 8], 0, 0, 0);
            ni[tn - 8] = __builtin_amdgcn_mfma_f32_16x16x32_bf16(mhi, bihl, ni[tn - 8], 0, 0, 0);
            ni[tn - 8] = __builtin_amdgcn_mfma_f32_16x16x32_bf16(mlo, bihh, ni[tn - 8], 0, 0, 0);
            nh[tn - 8] = __builtin_amdgcn_mfma_f32_16x16x32_bf16(hhi, bhhh, nh[tn - 8], 0, 0, 0);
            nh[tn - 8] = __builtin_amdgcn_mfma_f32_16x16x32_bf16(hhi, bhhl, nh[tn - 8], 0, 0, 0);
            nh[tn - 8] = __builtin_amdgcn_mfma_f32_16x16x32_bf16(hlo, bhhh, nh[tn - 8], 0, 0, 0);
        }
        PRIO0();
    }

    #pragma unroll
    for (int rr = 0; rr < 4; ++rr) {
        int rowl = wv * 16 + quad * 4 + rr;
        int grow = base + rowl;
        bool ok = grow < count;
        #pragma unroll
        for (int t = 0; t < 4; ++t) {
            int g = t * 16 + col;
            float rv = sigm(rz[t][rr] + bsr[t]);
            float zv = sigm(rz[4 + t][rr] + bsz[t]);
            float nv = tanh_f(ni[t][rr] + bin_[t] + rv * (nh[t][rr] + bhn[t]));
            if (ok) {
                float ho = Hs[rowl][g];
                hst[(size_t)grow * 64 + g] = (1.f - zv) * nv + zv * ho;
            }
            if (grow < nzero) nm[(size_t)grow * 64 + g] = 0.f;
        }
    }
}

// ---------- readout (unchanged) ----------
__global__ __launch_bounds__(256, 3)
void k_readout(const float* __restrict__ vh,
               const float* __restrict__ w1t, const float* __restrict__ b1,
               const float* __restrict__ w2t, const float* __restrict__ b2,
               const float* __restrict__ w3, const float* __restrict__ b3,
               float* __restrict__ out)
{
    __shared__ float H[HRDIM][64];
    const int lane = threadIdx.x & 63;
    const int wv   = __builtin_amdgcn_readfirstlane(threadIdx.x >> 6);
    const int n0 = blockIdx.x * 64 + lane;
    const int n  = n0 < NN ? n0 : NN - 1;
    const float4* px = (const float4*)(vh + (size_t)n * 64);

    const int j1 = 32 * wv;
    float acc[32];
    #pragma unroll
    for (int j = 0; j < 32; ++j) acc[j] = b1[j1 + j];
    #pragma unroll 4
    for (int q = 0; q < 16; ++q) {
        float4 x4 = px[q];
        const float* wa = w1t + (4 * q + 0) * HRDIM + j1;
        const float* wb = w1t + (4 * q + 1) * HRDIM + j1;
        const float* wc = w1t + (4 * q + 2) * HRDIM + j1;
        const float* wd = w1t + (4 * q + 3) * HRDIM + j1;
        #pragma unroll
        for (int j = 0; j < 32; ++j) {
            acc[j] = fmaf(wa[j], x4.x, acc[j]);
            acc[j] = fmaf(wb[j], x4.y, acc[j]);
            acc[j] = fmaf(wc[j], x4.z, acc[j]);
            acc[j] = fmaf(wd[j], x4.w, acc[j]);
        }
    }
    #pragma unroll
    for (int j = 0; j < 32; ++j) H[j1 + j][lane] = fmaxf(acc[j], 0.f);
    __syncthreads();

    #pragma unroll
    for (int j = 0; j < 32; ++j) acc[j] = b2[j1 + j];
    #pragma unroll 4
    for (int k = 0; k < HRDIM; ++k) {
        float xk = H[k][lane];
        const float* wr = w2t + k * HRDIM + j1;
        #pragma unroll
        for (int j = 0; j < 32; ++j)
            acc[j] = fmaf(wr[j], xk, acc[j]);
    }
    __syncthreads();
    #pragma unroll
    for (int j = 0; j < 32; ++j) H[j1 + j][lane] = fmaxf(acc[j], 0.f);
    __syncthreads();

    if (wv == 0 && n0 < NN) {
        float l0 = b3[0], l1 = b3[1];
        #pragma unroll 8
        for (int k = 0; k < HRDIM; ++k) {
            float hk = H[k][lane];
            l0 = fmaf(w3[k],         hk, l0);
            l1 = fmaf(w3[HRDIM + k], hk, l1);
        }
        float mx = fmaxf(l0, l1);
        float e0 = __expf(l0 - mx), e1 = __expf(l1 - mx);
        float inv = 1.f / (e0 + e1);
        out[2 * n + 0] = e0 * inv;
        out[2 * n + 1] = e1 * inv;
    }
}

// ---------- host ----------
extern "C" void kernel_launch(void* const* d_in, const int* in_sizes, int n_in,
                              void* d_out, int out_size, void* d_ws, size_t ws_size,
                              hipStream_t stream)
{
    float* var_h = (float*)d_ws;
    float* fac_h = var_h + 640000;
    float* nm    = fac_h + 5120000;
    float* ro_t  = nm + 5120000;            // 24,576 f32
    float* bsum  = ro_t + 24576;            // 384 f32 (2 x 192)
    unsigned short* pk = (unsigned short*)(bsum + 384); // 278,528 shorts

    const int*   f2v_row  = (const int*)d_in[0];
    const int*   f2v_col  = (const int*)d_in[1];
    const int*   v2f_row  = (const int*)d_in[2];
    const int*   v2f_col  = (const int*)d_in[3];
    const float* f2v_feat = (const float*)d_in[4];
    const float* v2f_feat = (const float*)d_in[5];
    const float* W[26];
    for (int j = 0; j < 26; ++j) W[j] = (const float*)d_in[6 + j];
    (void)f2v_row; (void)v2f_col;

    TArgs ta;
    float* T[NTR];
    {
        const float* src[NTR] = { W[20], W[22] };
        int R[NTR] = { HRDIM, HRDIM };
        int C[NTR] = { SDIM, HRDIM };
        size_t off = 0;
        for (int t = 0; t < NTR; ++t) {
            ta.src[t] = src[t]; ta.R[t] = R[t]; ta.C[t] = C[t];
            T[t] = ro_t + off; ta.dst[t] = T[t];
            off += (size_t)R[t] * C[t];
        }
    }
    unsigned short* P[12];
    unsigned short* G[8];
    {
        size_t off = 0;
        int esz[3] = { 20480, 16384, 8192 };
        for (int d = 0; d < 2; ++d)
            for (int m = 0; m < 3; ++m) {
                P[d * 6 + m * 2 + 0] = pk + off; off += esz[m];
                P[d * 6 + m * 2 + 1] = pk + off; off += esz[m];
            }
        for (int t = 0; t < 8; ++t) { G[t] = pk + off; off += 12288; }
    }
    PArgs pa;
    {
        const float* src[NPK] = { W[0], W[2], W[4], W[6], W[8], W[10],
                                  W[12], W[13], W[16], W[17] };
        int N[NPK]  = { HMDIM, HMDIM, SDIM,  HMDIM, HMDIM, SDIM,  192, 192, 192, 192 };
        int K[NPK]  = { KIN,   HMDIM, HMDIM, KIN,   HMDIM, HMDIM, SDIM, SDIM, SDIM, SDIM };
        int CK[NPK] = { 5,     4,     4,     5,     4,     4,     2,   2,   2,   2 };
        unsigned short* hi[NPK] = { P[0], P[2], P[4], P[6], P[8], P[10],
                                    G[0], G[2], G[4], G[6] };
        unsigned short* lo[NPK] = { P[1], P[3], P[5], P[7], P[9], P[11],
                                    G[1], G[3], G[5], G[7] };
        for (int t = 0; t < NPK; ++t) {
            pa.src[t] = src[t]; pa.N[t] = N[t]; pa.K[t] = K[t]; pa.CK[t] = CK[t];
            pa.hi[t] = hi[t];   pa.lo[t] = lo[t];
        }
    }
    k_transpose<<<NTR, 256, 0, stream>>>(ta);
    k_pack<<<NPK, 256, 0, stream>>>(pa);
    k_bsum<<<1, 256, 0, stream>>>(W[14], W[15], bsum, W[18], W[19], bsum + 192);
    k_zero<<<512, 256, 0, stream>>>(var_h, 640000 + 5120000 + 5120000);

    for (int s = 0; s < NSTEPS; ++s) {
        // fac -> var messages into nm[node] (atomic scatter); var GRU reads
        // nm and re-zeroes rows [0,NN) for the next step's atomics.
        k_edge_mfma<<<NE / 64, 256, 0, stream>>>(
            fac_h, var_h, f2v_col, f2v_feat,
            P[0], P[1], P[2], P[3], P[4], P[5],
            W[1], W[3], W[5], nm);
        k_gru_mfma<<<(NN + 63) / 64, 256, 0, stream>>>(
            nm, G[0], G[1], G[2], G[3], bsum, W[14], W[15], var_h, NN, NN);
        // var -> fac messages + fac GRU, fused (factor messages stay in LDS;
        // nm untouched in the factor region).
        k_edge_gru_fused<<<NE / 64, 256, 0, stream>>>(
            var_h, fac_h, v2f_row, v2f_feat,
            P[6], P[7], P[8], P[9], P[10], P[11],
            W[7], W[9], W[11],
            G[4], G[5], G[6], G[7], bsum + 192, W[18], W[19]);
    }
    k_readout<<<(NN + 63) / 64, 256, 0, stream>>>(
        var_h, T[0], W[21], T[1], W[23], W[24], W[25],
        (float*)d_out);
}

// Round 16
// 931.189 us; speedup vs baseline: 1.0583x; 1.0413x over previous
//
#include <hip/hip_runtime.h>
#include <hip/hip_bf16.h>

// Problem constants (fixed by reference setup)
#define NN     10000      // variable nodes
#define NF     80000      // factors
#define NE     160000     // directed edges per direction
#define SDIM   64         // state dim
#define HMDIM  128        // hidden (message MLP)
#define HRDIM  128        // hidden (readout)
#define KIN    136        // 2*S + 8
#define NSTEPS 5

static_assert(NE % 64 == 0, "edge grid exact");

typedef __attribute__((ext_vector_type(8))) short short8;   // 8 bf16 = 4 VGPRs
typedef __attribute__((ext_vector_type(4))) float f32x4;    // MFMA C/D

// ---------- helpers ----------
static __device__ __forceinline__ float bf2f(unsigned short u) {
    return __uint_as_float(((unsigned int)u) << 16);
}
// R4: pure fp16 fails absmax; 3-MFMA bf16 hi/lo is the numerics floor.
// R9: direct-global B for the edge MLP is latency-bound; staged-LDS only.
// R12: single-barrier phases + gl stride pad both regressed.
// R13/R14: fused layer-3 staging loop needed its trailing barrier (race).
// R15: H tile stored as f32 [64][132] (33.8KB ~= old hi/lo 34.8KB), split8
// on READ at chunk boundaries. Numerics BIT-IDENTICAL (split8(v) at read
// equals the previously stored hi/lo pair); saves ~190 VALU ops/wave of
// epilogue converts (VALUBusy 34% was the top pipe). 2-way LDS conflicts
// on stride-132 f32 access are free (m136). This is R7's idea with the
// CORRECT 128-wide array (R7 died on a [64][68] width bug, not the concept).
static __device__ __forceinline__ unsigned short f2bf(float f) {
    __hip_bfloat16 h = __float2bfloat16(f);
    unsigned short u;
    __builtin_memcpy(&u, &h, 2);
    return u;
}
static __device__ __forceinline__ float sigm(float x) {
    x = fminf(fmaxf(x, -30.f), 30.f);
    return 1.f / (1.f + __expf(-x));
}
static __device__ __forceinline__ float tanh_f(float x) {
    x = fminf(fmaxf(x, -15.f), 15.f);
    float t = __expf(2.f * x);
    return (t - 1.f) / (t + 1.f);
}
// split f32 -> bf16 hi + bf16 lo (x ~= hi + lo, ~16 mantissa bits kept)
static __device__ __forceinline__ void split8(const float* x, short8& hi, short8& lo) {
    #pragma unroll
    for (int i = 0; i < 8; ++i) {
        unsigned short h = f2bf(x[i]);
        hi[i] = (short)h;
        lo[i] = (short)f2bf(x[i] - bf2f(h));
    }
}
static __device__ __forceinline__ void f4pair_to8(float4 a, float4 b, float* xv) {
    xv[0]=a.x; xv[1]=a.y; xv[2]=a.z; xv[3]=a.w;
    xv[4]=b.x; xv[5]=b.y; xv[6]=b.z; xv[7]=b.w;
}
// async global->LDS DMA, 16B per lane, no VGPR round-trip (tracked by vmcnt)
static __device__ __forceinline__ void dma16(const unsigned short* g, unsigned short* l) {
    __builtin_amdgcn_global_load_lds(
        (const __attribute__((address_space(1))) void*)g,
        (__attribute__((address_space(3))) void*)l,
        16, 0, 0);
}

#define LGKM0() asm volatile("s_waitcnt lgkmcnt(0)" ::: "memory")
#define VMC2()  asm volatile("s_waitcnt vmcnt(2)"   ::: "memory")
#define VMC0()  asm volatile("s_waitcnt vmcnt(0)"   ::: "memory")
#define SBAR()  __builtin_amdgcn_s_barrier()
#define SCHED0() __builtin_amdgcn_sched_barrier(0)
#define PRIO1() __builtin_amdgcn_s_setprio(1)
#define PRIO0() __builtin_amdgcn_s_setprio(0)

__global__ void k_zero(float* __restrict__ p, int n) {
    int i = blockIdx.x * blockDim.x + threadIdx.x;
    int stride = gridDim.x * blockDim.x;
    for (; i < n; i += stride) p[i] = 0.f;
}

// ---------- weight transpose for readout (dst[k][j] = src[j][k]) ----------
#define NTR 2
struct TArgs {
    const float* src[NTR];
    float*       dst[NTR];
    int          R[NTR];
    int          C[NTR];
};
__global__ void k_transpose(TArgs a) {
    const int b = blockIdx.x;
    const float* s = a.src[b];
    float* d = a.dst[b];
    const int R = a.R[b], C = a.C[b], n = R * C;
    for (int i = threadIdx.x; i < n; i += blockDim.x) {
        int r = i / C, c = i % C;
        d[c * R + r] = s[i];
    }
}

// ---------- pack weights into B-fragment streams (hi/lo bf16) ----------
#define NPK 10
struct PArgs {
    const float*    src[NPK];
    unsigned short* hi[NPK];
    unsigned short* lo[NPK];
    int             N[NPK], K[NPK], CK[NPK];
};
__global__ void k_pack(PArgs a) {
    const int b = blockIdx.x;
    const float* s = a.src[b];
    unsigned short* ph = a.hi[b];
    unsigned short* pl = a.lo[b];
    const int N = a.N[b], K = a.K[b], CK = a.CK[b];
    const int NT = N >> 4;
    const int total = NT * CK * 512;
    for (int i = threadIdx.x; i < total; i += blockDim.x) {
        int j    = i & 7;
        int ln   = (i >> 3) & 63;
        int tile = i >> 9;
        int tn   = tile % NT;
        int ck   = tile / NT;
        int k = ck * 32 + ((ln >> 4) * 8) + j;
        int n = tn * 16 + (ln & 15);
        float f = (k < K) ? s[n * K + k] : 0.f;
        unsigned short h = f2bf(f);
        ph[i] = h;
        pl[i] = f2bf(f - bf2f(h));
    }
}

// bias sums for GRU r/z gates: o[j] = bih[j] + bhh[j], j in [0,192)
__global__ void k_bsum(const float* bih0, const float* bhh0, float* o0,
                       const float* bih1, const float* bhh1, float* o1) {
    int i = threadIdx.x;
    if (i < 192) { o0[i] = bih0[i] + bhh0[i]; o1[i] = bih1[i] + bhh1[i]; }
}

// ---- half-phase B staging: 4KB hi + 4KB lo per half-phase, dbuf 16KB ----
#define STAGE(buf, sh, sl) do {                                            \
    const int u0_ = wv * 2;                                                \
    _Pragma("unroll")                                                      \
    for (int k_ = 0; k_ < 2; ++k_) {                                       \
        const int u_ = u0_ + k_;                                           \
        const unsigned short* s_ = (u_ < 4 ? (sh) : (sl)) + (u_ & 3) * 512;\
        unsigned short* d_ = (u_ < 4 ? &BH[buf][0] : &BL[buf][0]) + (u_ & 3) * 512; \
        dma16(s_ + lane * 8, d_);                                          \
    }                                                                      \
} while (0)

// read 8 floats from Hf row m0 at column c0, split to bf16 hi/lo frags
#define A_FROM_HF(dsthi, dstlo, c0_) do {                                  \
    float xv_[8];                                                          \
    *(float4*)&xv_[0] = *(const float4*)(&Hf[m0][(c0_)]);                  \
    *(float4*)&xv_[4] = *(const float4*)(&Hf[m0][(c0_) + 4]);              \
    split8(xv_, dsthi, dstlo);                                             \
} while (0)

// ---------- f2v MFMA edge MLP + atomic scatter ----------
__global__ __launch_bounds__(256, 3)
void k_edge_mfma(const float* __restrict__ hrow, const float* __restrict__ hcol,
                 const int* __restrict__ cols,
                 const float* __restrict__ feat,
                 const unsigned short* __restrict__ w1h, const unsigned short* __restrict__ w1l,
                 const unsigned short* __restrict__ w2h, const unsigned short* __restrict__ w2l,
                 const unsigned short* __restrict__ w3h, const unsigned short* __restrict__ w3l,
                 const float* __restrict__ b1, const float* __restrict__ b2,
                 const float* __restrict__ b3,
                 float* __restrict__ nm)
{
    __shared__ __align__(16) float Hf[64][132];             // 33.8 KB (f32 H)
    __shared__ __align__(16) unsigned short BH[2][2048];    // 8 KB (dbuf hi)
    __shared__ __align__(16) unsigned short BL[2][2048];    // 8 KB (dbuf lo)
    const int lane = threadIdx.x & 63;
    const int wv   = threadIdx.x >> 6;        // 0..3
    const int quad = lane >> 4;               // 0..3
    const int col  = lane & 15;

    const int e0 = blockIdx.x * 64 + wv * 16 + col;
    const int r0 = e0 >> 1;                   // f2v rows = fidx = e/2
    const int c0 = cols[e0];

    float4 gR[4], gC[4], gFr, gFc;
    {
        const float4* pr = (const float4*)(hrow + (size_t)r0 * 64);
        const float4* pc = (const float4*)(hcol + (size_t)c0 * 64);
        gR[0] = pr[quad * 2];     gR[1] = pr[quad * 2 + 1];
        gR[2] = pr[8 + quad * 2]; gR[3] = pr[8 + quad * 2 + 1];
        gC[0] = pc[quad * 2];     gC[1] = pc[quad * 2 + 1];
        gC[2] = pc[8 + quad * 2]; gC[3] = pc[8 + quad * 2 + 1];
        gFr = *(const float4*)(feat + (size_t)r0 * 4);
        gFc = *(const float4*)(feat + (size_t)c0 * 4);
    }
    int cc[4];
    #pragma unroll
    for (int rr = 0; rr < 4; ++rr)
        cc[rr] = cols[blockIdx.x * 64 + wv * 16 + quad * 4 + rr];

    float b1v[8], b2v[8], b3v[4];
    #pragma unroll
    for (int t = 0; t < 8; ++t) { b1v[t] = b1[t * 16 + col]; b2v[t] = b2[t * 16 + col]; }
    #pragma unroll
    for (int t = 0; t < 4; ++t) b3v[t] = b3[t * 16 + col];

    VMC0(); SCHED0();
    STAGE(0, w1h, w1l);

    f32x4 acc[8];
    #pragma unroll
    for (int t = 0; t < 8; ++t) acc[t] = (f32x4){0.f, 0.f, 0.f, 0.f};

    short8 ahi, alo;
    #pragma unroll
    for (int hp = 0; hp < 10; ++hp) {
        {
            const unsigned short* nh; const unsigned short* nl;
            if (hp < 9) { nh = w1h + (hp + 1) * 2048; nl = w1l + (hp + 1) * 2048; }
            else        { nh = w2h;                   nl = w2l; }
            STAGE((hp + 1) & 1, nh, nl);
        }
        if ((hp & 1) == 0) {
            const int ck = hp >> 1;
            float xv[8];
            if (ck < 2)      f4pair_to8(gR[ck * 2], gR[ck * 2 + 1], xv);
            else if (ck < 4) f4pair_to8(gC[(ck - 2) * 2], gC[(ck - 2) * 2 + 1], xv);
            else if (quad == 0) f4pair_to8(gFr, gFc, xv);
            else {
                #pragma unroll
                for (int i = 0; i < 8; ++i) xv[i] = 0.f;
            }
            split8(xv, ahi, alo);
        }
        VMC2(); LGKM0(); SBAR(); SCHED0();
        {
            const unsigned short* bh = &BH[hp & 1][0];
            const unsigned short* bl = &BL[hp & 1][0];
            #pragma unroll
            for (int t = 0; t < 4; ++t) {
                const int tn = (hp & 1) * 4 + t;
                short8 bhi = *(const short8*)(bh + t * 512 + lane * 8);
                short8 blo = *(const short8*)(bl + t * 512 + lane * 8);
                acc[tn] = __builtin_amdgcn_mfma_f32_16x16x32_bf16(ahi, bhi, acc[tn], 0, 0, 0);
                acc[tn] = __builtin_amdgcn_mfma_f32_16x16x32_bf16(ahi, blo, acc[tn], 0, 0, 0);
                acc[tn] = __builtin_amdgcn_mfma_f32_16x16x32_bf16(alo, bhi, acc[tn], 0, 0, 0);
            }
        }
        LGKM0(); SBAR(); SCHED0();
    }
    // epilogue 1: bias + relu -> Hf (f32, wave-private rows; no converts)
    #pragma unroll
    for (int tn = 0; tn < 8; ++tn)
        #pragma unroll
        for (int rr = 0; rr < 4; ++rr)
            Hf[wv * 16 + quad * 4 + rr][tn * 16 + col] =
                fmaxf(acc[tn][rr] + b1v[tn], 0.f);

    #pragma unroll
    for (int t = 0; t < 8; ++t) acc[t] = (f32x4){0.f, 0.f, 0.f, 0.f};
    const int m0 = wv * 16 + col;
    #pragma unroll
    for (int h2 = 0; h2 < 8; ++h2) {
        const int hp = 10 + h2;
        {
            const unsigned short* nh; const unsigned short* nl;
            if (h2 < 7) { nh = w2h + (h2 + 1) * 2048; nl = w2l + (h2 + 1) * 2048; }
            else        { nh = w3h;                   nl = w3l; }
            STAGE((hp + 1) & 1, nh, nl);
        }
        if ((h2 & 1) == 0) {
            const int ck = h2 >> 1;
            A_FROM_HF(ahi, alo, ck * 32 + quad * 8);
        }
        VMC2(); LGKM0(); SBAR(); SCHED0();
        {
            const unsigned short* bh = &BH[hp & 1][0];
            const unsigned short* bl = &BL[hp & 1][0];
            #pragma unroll
            for (int t = 0; t < 4; ++t) {
                const int tn = (h2 & 1) * 4 + t;
                short8 bhi = *(const short8*)(bh + t * 512 + lane * 8);
                short8 blo = *(const short8*)(bl + t * 512 + lane * 8);
                acc[tn] = __builtin_amdgcn_mfma_f32_16x16x32_bf16(ahi, bhi, acc[tn], 0, 0, 0);
                acc[tn] = __builtin_amdgcn_mfma_f32_16x16x32_bf16(ahi, blo, acc[tn], 0, 0, 0);
                acc[tn] = __builtin_amdgcn_mfma_f32_16x16x32_bf16(alo, bhi, acc[tn], 0, 0, 0);
            }
        }
        LGKM0(); SBAR(); SCHED0();
    }
    // epilogue 2 (f32, wave-private rows)
    #pragma unroll
    for (int tn = 0; tn < 8; ++tn)
        #pragma unroll
        for (int rr = 0; rr < 4; ++rr)
            Hf[wv * 16 + quad * 4 + rr][tn * 16 + col] =
                fmaxf(acc[tn][rr] + b2v[tn], 0.f);

    f32x4 a3[4];
    #pragma unroll
    for (int t = 0; t < 4; ++t) a3[t] = (f32x4){0.f, 0.f, 0.f, 0.f};
    #pragma unroll
    for (int h3 = 0; h3 < 4; ++h3) {
        const int hp = 18 + h3;
        if (h3 < 3) STAGE((hp + 1) & 1, w3h + (h3 + 1) * 2048, w3l + (h3 + 1) * 2048);
        short8 a3h, a3l;
        A_FROM_HF(a3h, a3l, h3 * 32 + quad * 8);
        if (h3 < 3) { VMC2(); } else { VMC0(); }
        LGKM0(); SBAR(); SCHED0();
        {
            const unsigned short* bh = &BH[hp & 1][0];
            const unsigned short* bl = &BL[hp & 1][0];
            #pragma unroll
            for (int t = 0; t < 4; ++t) {
                short8 bhi = *(const short8*)(bh + t * 512 + lane * 8);
                short8 blo = *(const short8*)(bl + t * 512 + lane * 8);
                a3[t] = __builtin_amdgcn_mfma_f32_16x16x32_bf16(a3h, bhi, a3[t], 0, 0, 0);
                a3[t] = __builtin_amdgcn_mfma_f32_16x16x32_bf16(a3h, blo, a3[t], 0, 0, 0);
                a3[t] = __builtin_amdgcn_mfma_f32_16x16x32_bf16(a3l, bhi, a3[t], 0, 0, 0);
            }
        }
        if (h3 < 3) { LGKM0(); SBAR(); SCHED0(); }
    }

    #pragma unroll
    for (int tn = 0; tn < 4; ++tn) {
        float bias = b3v[tn];
        #pragma unroll
        for (int rr = 0; rr < 4; ++rr)
            atomicAdd(&nm[(size_t)cc[rr] * 64 + tn * 16 + col], a3[tn][rr] + bias);
    }
}

// ---------- FUSED v2f edge MLP + fac GRU ----------
__global__ __launch_bounds__(256, 3)
void k_edge_gru_fused(const float* __restrict__ hrow, float* fstate,
                      const int* __restrict__ rows,
                      const float* __restrict__ feat,
                      const unsigned short* __restrict__ w1h, const unsigned short* __restrict__ w1l,
                      const unsigned short* __restrict__ w2h, const unsigned short* __restrict__ w2l,
                      const unsigned short* __restrict__ w3h, const unsigned short* __restrict__ w3l,
                      const float* __restrict__ b1, const float* __restrict__ b2,
                      const float* __restrict__ b3,
                      const unsigned short* __restrict__ gih_h, const unsigned short* __restrict__ gih_l,
                      const unsigned short* __restrict__ ghh_h, const unsigned short* __restrict__ ghh_l,
                      const float* __restrict__ bsum, const float* __restrict__ bih,
                      const float* __restrict__ bhh)
{
    // 51200B arena. Phase-1: Hf f32 [0,33792) | BH [33792,41984) |
    // BL [41984,50176). Phase-2 overlays (behind barrier A, all phase-1
    // regions dead): nmL = [0,8704) float[32][68]; gl = [8704,41984)
    // float[32][260].
    __shared__ __align__(16) unsigned char SM[51200];
    float (*Hf)[132] = (float(*)[132])(SM);
    unsigned short (*BH)[2048] = (unsigned short(*)[2048])(SM + 33792);
    unsigned short (*BL)[2048] = (unsigned short(*)[2048])(SM + 41984);
    float (*nmL)[68]  = (float(*)[68])(SM);
    float (*gl)[260]  = (float(*)[260])(SM + 8704);

    const int lane = threadIdx.x & 63;
    const int wv   = threadIdx.x >> 6;        // 0..3
    const int quad = lane >> 4;               // 0..3
    const int col  = lane & 15;

    const int e0 = blockIdx.x * 64 + wv * 16 + col;
    const int r0 = rows[e0];                  // variable endpoint
    const int c0 = e0 >> 1;                   // v2f cols = fidx = e/2

    float4 gR[4], gC[4], gFr, gFc;
    {
        const float4* pr = (const float4*)(hrow + (size_t)r0 * 64);
        const float4* pc = (const float4*)(fstate + (size_t)c0 * 64);
        gR[0] = pr[quad * 2];     gR[1] = pr[quad * 2 + 1];
        gR[2] = pr[8 + quad * 2]; gR[3] = pr[8 + quad * 2 + 1];
        gC[0] = pc[quad * 2];     gC[1] = pc[quad * 2 + 1];
        gC[2] = pc[8 + quad * 2]; gC[3] = pc[8 + quad * 2 + 1];
        gFr = *(const float4*)(feat + (size_t)r0 * 4);
        gFc = *(const float4*)(feat + (size_t)c0 * 4);
    }
    float b1v[8], b2v[8], b3v[4];
    #pragma unroll
    for (int t = 0; t < 8; ++t) { b1v[t] = b1[t * 16 + col]; b2v[t] = b2[t * 16 + col]; }
    #pragma unroll
    for (int t = 0; t < 4; ++t) b3v[t] = b3[t * 16 + col];

    VMC0(); SCHED0();
    STAGE(0, w1h, w1l);

    f32x4 acc[8];
    #pragma unroll
    for (int t = 0; t < 8; ++t) acc[t] = (f32x4){0.f, 0.f, 0.f, 0.f};

    short8 ahi, alo;
    #pragma unroll
    for (int hp = 0; hp < 10; ++hp) {
        {
            const unsigned short* nh; const unsigned short* nl;
            if (hp < 9) { nh = w1h + (hp + 1) * 2048; nl = w1l + (hp + 1) * 2048; }
            else        { nh = w2h;                   nl = w2l; }
            STAGE((hp + 1) & 1, nh, nl);
        }
        if ((hp & 1) == 0) {
            const int ck = hp >> 1;
            float xv[8];
            if (ck < 2)      f4pair_to8(gR[ck * 2], gR[ck * 2 + 1], xv);
            else if (ck < 4) f4pair_to8(gC[(ck - 2) * 2], gC[(ck - 2) * 2 + 1], xv);
            else if (quad == 0) f4pair_to8(gFr, gFc, xv);
            else {
                #pragma unroll
                for (int i = 0; i < 8; ++i) xv[i] = 0.f;
            }
            split8(xv, ahi, alo);
        }
        VMC2(); LGKM0(); SBAR(); SCHED0();
        {
            const unsigned short* bh = &BH[hp & 1][0];
            const unsigned short* bl = &BL[hp & 1][0];
            #pragma unroll
            for (int t = 0; t < 4; ++t) {
                const int tn = (hp & 1) * 4 + t;
                short8 bhi = *(const short8*)(bh + t * 512 + lane * 8);
                short8 blo = *(const short8*)(bl + t * 512 + lane * 8);
                acc[tn] = __builtin_amdgcn_mfma_f32_16x16x32_bf16(ahi, bhi, acc[tn], 0, 0, 0);
                acc[tn] = __builtin_amdgcn_mfma_f32_16x16x32_bf16(ahi, blo, acc[tn], 0, 0, 0);
                acc[tn] = __builtin_amdgcn_mfma_f32_16x16x32_bf16(alo, bhi, acc[tn], 0, 0, 0);
            }
        }
        LGKM0(); SBAR(); SCHED0();
    }
    #pragma unroll
    for (int tn = 0; tn < 8; ++tn)
        #pragma unroll
        for (int rr = 0; rr < 4; ++rr)
            Hf[wv * 16 + quad * 4 + rr][tn * 16 + col] =
                fmaxf(acc[tn][rr] + b1v[tn], 0.f);

    #pragma unroll
    for (int t = 0; t < 8; ++t) acc[t] = (f32x4){0.f, 0.f, 0.f, 0.f};
    const int m0 = wv * 16 + col;
    #pragma unroll
    for (int h2 = 0; h2 < 8; ++h2) {
        const int hp = 10 + h2;
        {
            const unsigned short* nh; const unsigned short* nl;
            if (h2 < 7) { nh = w2h + (h2 + 1) * 2048; nl = w2l + (h2 + 1) * 2048; }
            else        { nh = w3h;                   nl = w3l; }
            STAGE((hp + 1) & 1, nh, nl);
        }
        if ((h2 & 1) == 0) {
            const int ck = h2 >> 1;
            A_FROM_HF(ahi, alo, ck * 32 + quad * 8);
        }
        VMC2(); LGKM0(); SBAR(); SCHED0();
        {
            const unsigned short* bh = &BH[hp & 1][0];
            const unsigned short* bl = &BL[hp & 1][0];
            #pragma unroll
            for (int t = 0; t < 4; ++t) {
                const int tn = (h2 & 1) * 4 + t;
                short8 bhi = *(const short8*)(bh + t * 512 + lane * 8);
                short8 blo = *(const short8*)(bl + t * 512 + lane * 8);
                acc[tn] = __builtin_amdgcn_mfma_f32_16x16x32_bf16(ahi, bhi, acc[tn], 0, 0, 0);
                acc[tn] = __builtin_amdgcn_mfma_f32_16x16x32_bf16(ahi, blo, acc[tn], 0, 0, 0);
                acc[tn] = __builtin_amdgcn_mfma_f32_16x16x32_bf16(alo, bhi, acc[tn], 0, 0, 0);
            }
        }
        LGKM0(); SBAR(); SCHED0();
    }
    #pragma unroll
    for (int tn = 0; tn < 8; ++tn)
        #pragma unroll
        for (int rr = 0; rr < 4; ++rr)
            Hf[wv * 16 + quad * 4 + rr][tn * 16 + col] =
                fmaxf(acc[tn][rr] + b2v[tn], 0.f);

    f32x4 a3[4];
    #pragma unroll
    for (int t = 0; t < 4; ++t) a3[t] = (f32x4){0.f, 0.f, 0.f, 0.f};
    #pragma unroll
    for (int h3 = 0; h3 < 4; ++h3) {
        const int hp = 18 + h3;
        if (h3 < 3) STAGE((hp + 1) & 1, w3h + (h3 + 1) * 2048, w3l + (h3 + 1) * 2048);
        short8 a3h, a3l;
        A_FROM_HF(a3h, a3l, h3 * 32 + quad * 8);
        if (h3 < 3) { VMC2(); } else { VMC0(); }
        LGKM0(); SBAR(); SCHED0();
        {
            const unsigned short* bh = &BH[hp & 1][0];
            const unsigned short* bl = &BL[hp & 1][0];
            #pragma unroll
            for (int t = 0; t < 4; ++t) {
                short8 bhi = *(const short8*)(bh + t * 512 + lane * 8);
                short8 blo = *(const short8*)(bl + t * 512 + lane * 8);
                a3[t] = __builtin_amdgcn_mfma_f32_16x16x32_bf16(a3h, bhi, a3[t], 0, 0, 0);
                a3[t] = __builtin_amdgcn_mfma_f32_16x16x32_bf16(a3h, blo, a3[t], 0, 0, 0);
                a3[t] = __builtin_amdgcn_mfma_f32_16x16x32_bf16(a3l, bhi, a3[t], 0, 0, 0);
            }
        }
        // trailing barrier (R14 fix): next STAGE overwrites the buffer
        // these MFMAs read; keep waves separated.
        if (h3 < 3) { LGKM0(); SBAR(); SCHED0(); }
    }

    // ---- barrier A: every wave done with Hf/B reads -> overlays safe
    LGKM0(); SBAR(); SCHED0();

    // pairsum -> nmL (factor message tile, rows = local factor 0..31)
    {
        int lf0 = wv * 8 + quad * 2;
        #pragma unroll
        for (int tn = 0; tn < 4; ++tn) {
            float b2x = 2.f * b3v[tn];
            nmL[lf0][tn * 16 + col]     = a3[tn][0] + a3[tn][1] + b2x;
            nmL[lf0 + 1][tn * 16 + col] = a3[tn][2] + a3[tn][3] + b2x;
        }
    }
    LGKM0(); SBAR(); SCHED0();   // barrier B: nmL visible to all waves

    // ---- fused fac GRU: 32 factors, wave = (Mhalf mt, Nhalf half) ----
    const int fbase = blockIdx.x * 32;
    const int mt    = wv >> 1;             // 16-row M-tile
    const int half  = wv & 1;              // gate-tile half (6 of 12)
    const int hrow0 = fbase + mt * 16 + col;

    if (half == 0) {
        f32x4 rz6[6];
        #pragma unroll
        for (int i = 0; i < 6; ++i) rz6[i] = (f32x4){0.f, 0.f, 0.f, 0.f};
        #pragma unroll
        for (int ck = 0; ck < 2; ++ck) {
            short8 mhi, mlo, hhi, hlo;
            {
                float xv[8];
                *(float4*)&xv[0] = *(const float4*)(&nmL[mt * 16 + col][ck * 32 + quad * 8]);
                *(float4*)&xv[4] = *(const float4*)(&nmL[mt * 16 + col][ck * 32 + quad * 8 + 4]);
                split8(xv, mhi, mlo);
                const float* hp_ = fstate + (size_t)hrow0 * 64 + ck * 32 + quad * 8;
                *(float4*)&xv[0] = *(const float4*)(hp_);
                *(float4*)&xv[4] = *(const float4*)(hp_ + 4);
                split8(xv, hhi, hlo);
            }
            const unsigned short* ih = gih_h + (size_t)(ck * 12) * 512 + lane * 8;
            const unsigned short* il = gih_l + (size_t)(ck * 12) * 512 + lane * 8;
            const unsigned short* hh = ghh_h + (size_t)(ck * 12) * 512 + lane * 8;
            const unsigned short* hl = ghh_l + (size_t)(ck * 12) * 512 + lane * 8;
            #pragma unroll
            for (int i = 0; i < 6; ++i) {
                short8 bihh = *(const short8*)(ih + i * 512);
                short8 bihl = *(const short8*)(il + i * 512);
                short8 bhhh = *(const short8*)(hh + i * 512);
                short8 bhhl = *(const short8*)(hl + i * 512);
                rz6[i] = __builtin_amdgcn_mfma_f32_16x16x32_bf16(mhi, bihh, rz6[i], 0, 0, 0);
                rz6[i] = __builtin_amdgcn_mfma_f32_16x16x32_bf16(mhi, bihl, rz6[i], 0, 0, 0);
                rz6[i] = __builtin_amdgcn_mfma_f32_16x16x32_bf16(mlo, bihh, rz6[i], 0, 0, 0);
                rz6[i] = __builtin_amdgcn_mfma_f32_16x16x32_bf16(hhi, bhhh, rz6[i], 0, 0, 0);
                rz6[i] = __builtin_amdgcn_mfma_f32_16x16x32_bf16(hhi, bhhl, rz6[i], 0, 0, 0);
                rz6[i] = __builtin_amdgcn_mfma_f32_16x16x32_bf16(hlo, bhhh, rz6[i], 0, 0, 0);
            }
        }
        #pragma unroll
        for (int i = 0; i < 6; ++i)
            #pragma unroll
            for (int rr = 0; rr < 4; ++rr)
                gl[mt * 16 + quad * 4 + rr][i * 16 + col] = rz6[i][rr];
    } else {
        f32x4 rz2[2], niA[4], nhA[4];
        #pragma unroll
        for (int i = 0; i < 2; ++i) rz2[i] = (f32x4){0.f, 0.f, 0.f, 0.f};
        #pragma unroll
        for (int i = 0; i < 4; ++i) {
            niA[i] = (f32x4){0.f, 0.f, 0.f, 0.f};
            nhA[i] = (f32x4){0.f, 0.f, 0.f, 0.f};
        }
        #pragma unroll
        for (int ck = 0; ck < 2; ++ck) {
            short8 mhi, mlo, hhi, hlo;
            {
                float xv[8];
                *(float4*)&xv[0] = *(const float4*)(&nmL[mt * 16 + col][ck * 32 + quad * 8]);
                *(float4*)&xv[4] = *(const float4*)(&nmL[mt * 16 + col][ck * 32 + quad * 8 + 4]);
                split8(xv, mhi, mlo);
                const float* hp_ = fstate + (size_t)hrow0 * 64 + ck * 32 + quad * 8;
                *(float4*)&xv[0] = *(const float4*)(hp_);
                *(float4*)&xv[4] = *(const float4*)(hp_ + 4);
                split8(xv, hhi, hlo);
            }
            const unsigned short* ih = gih_h + (size_t)(ck * 12) * 512 + lane * 8;
            const unsigned short* il = gih_l + (size_t)(ck * 12) * 512 + lane * 8;
            const unsigned short* hh = ghh_h + (size_t)(ck * 12) * 512 + lane * 8;
            const unsigned short* hl = ghh_l + (size_t)(ck * 12) * 512 + lane * 8;
            #pragma unroll
            for (int i = 0; i < 2; ++i) {          // rz tiles 6,7
                const int tn = 6 + i;
                short8 bihh = *(const short8*)(ih + tn * 512);
                short8 bihl = *(const short8*)(il + tn * 512);
                short8 bhhh = *(const short8*)(hh + tn * 512);
                short8 bhhl = *(const short8*)(hl + tn * 512);
                rz2[i] = __builtin_amdgcn_mfma_f32_16x16x32_bf16(mhi, bihh, rz2[i], 0, 0, 0);
                rz2[i] = __builtin_amdgcn_mfma_f32_16x16x32_bf16(mhi, bihl, rz2[i], 0, 0, 0);
                rz2[i] = __builtin_amdgcn_mfma_f32_16x16x32_bf16(mlo, bihh, rz2[i], 0, 0, 0);
                rz2[i] = __builtin_amdgcn_mfma_f32_16x16x32_bf16(hhi, bhhh, rz2[i], 0, 0, 0);
                rz2[i] = __builtin_amdgcn_mfma_f32_16x16x32_bf16(hhi, bhhl, rz2[i], 0, 0, 0);
                rz2[i] = __builtin_amdgcn_mfma_f32_16x16x32_bf16(hlo, bhhh, rz2[i], 0, 0, 0);
            }
            #pragma unroll
            for (int i = 0; i < 4; ++i) {          // n tiles 8..11
                const int tn = 8 + i;
                short8 bihh = *(const short8*)(ih + tn * 512);
                short8 bihl = *(const short8*)(il + tn * 512);
                short8 bhhh = *(const short8*)(hh + tn * 512);
                short8 bhhl = *(const short8*)(hl + tn * 512);
                niA[i] = __builtin_amdgcn_mfma_f32_16x16x32_bf16(mhi, bihh, niA[i], 0, 0, 0);
                niA[i] = __builtin_amdgcn_mfma_f32_16x16x32_bf16(mhi, bihl, niA[i], 0, 0, 0);
                niA[i] = __builtin_amdgcn_mfma_f32_16x16x32_bf16(mlo, bihh, niA[i], 0, 0, 0);
                nhA[i] = __builtin_amdgcn_mfma_f32_16x16x32_bf16(hhi, bhhh, nhA[i], 0, 0, 0);
                nhA[i] = __builtin_amdgcn_mfma_f32_16x16x32_bf16(hhi, bhhl, nhA[i], 0, 0, 0);
                nhA[i] = __builtin_amdgcn_mfma_f32_16x16x32_bf16(hlo, bhhh, nhA[i], 0, 0, 0);
            }
        }
        #pragma unroll
        for (int rr = 0; rr < 4; ++rr) {
            const int gr = mt * 16 + quad * 4 + rr;
            #pragma unroll
            for (int i = 0; i < 2; ++i) gl[gr][(6 + i) * 16 + col] = rz2[i][rr];
            #pragma unroll
            for (int i = 0; i < 4; ++i) {
                gl[gr][128 + i * 16 + col] = niA[i][rr];
                gl[gr][192 + i * 16 + col] = nhA[i][rr];
            }
        }
    }
    LGKM0(); SBAR(); SCHED0();   // barrier C: gate tiles visible

    // combine: 32 rows x 64 outputs, 8 per thread; one thread per output.
    {
        const int r  = threadIdx.x >> 3;
        const int g0 = (threadIdx.x & 7) * 8;
        const size_t gw = (size_t)(fbase + r) * 64;
        #pragma unroll
        for (int j = 0; j < 8; ++j) {
            const int g = g0 + j;
            float rv = sigm(gl[r][g] + bsum[g]);
            float zv = sigm(gl[r][64 + g] + bsum[64 + g]);
            float nv = tanh_f(gl[r][128 + g] + bih[128 + g]
                              + rv * (gl[r][192 + g] + bhh[128 + g]));
            float ho = fstate[gw + g];
            fstate[gw + g] = (1.f - zv) * nv + zv * ho;
        }
    }
}

// ---------- MFMA GRU: h = GRU(nm, h), bf16 hi/lo, 4 waves x 16 rows ----------
// (var nodes only; nzero=NN re-zeroes nm for next step's f2v atomics.)
__global__ __launch_bounds__(256, 3)
void k_gru_mfma(float* __restrict__ nm,
                const unsigned short* __restrict__ wih_h, const unsigned short* __restrict__ wih_l,
                const unsigned short* __restrict__ whh_h, const unsigned short* __restrict__ whh_l,
                const float* __restrict__ bsum,          // bih+bhh [192]
                const float* __restrict__ bih, const float* __restrict__ bhh,
                float* __restrict__ hst, int count, int nzero)
{
    __shared__ float Hs[64][68];              // 17.4 KB, stride-68 conflict-free
    const int lane = threadIdx.x & 63;
    const int wv   = threadIdx.x >> 6;        // 0..3
    const int quad = lane >> 4;
    const int col  = lane & 15;
    const int base = blockIdx.x * 64;

    float4 am[4], ah[4];
    {
        int ra = base + wv * 16 + col;
        ra = ra < count ? ra : count - 1;
        const float4* pm = (const float4*)(nm + (size_t)ra * 64);
        const float4* ph = (const float4*)(hst + (size_t)ra * 64);
        am[0] = pm[quad * 2];     am[1] = pm[quad * 2 + 1];
        am[2] = pm[8 + quad * 2]; am[3] = pm[8 + quad * 2 + 1];
        ah[0] = ph[quad * 2];     ah[1] = ph[quad * 2 + 1];
        ah[2] = ph[8 + quad * 2]; ah[3] = ph[8 + quad * 2 + 1];
    }
    float bsr[4], bsz[4], bin_[4], bhn[4];
    #pragma unroll
    for (int t = 0; t < 4; ++t) {
        int g = t * 16 + col;
        bsr[t] = bsum[g]; bsz[t] = bsum[64 + g];
        bin_[t] = bih[128 + g]; bhn[t] = bhh[128 + g];
    }
    {
        int rowl = wv * 16 + col;
        *(float4*)(&Hs[rowl][quad * 8])          = ah[0];
        *(float4*)(&Hs[rowl][quad * 8 + 4])      = ah[1];
        *(float4*)(&Hs[rowl][32 + quad * 8])     = ah[2];
        *(float4*)(&Hs[rowl][32 + quad * 8 + 4]) = ah[3];
    }

    f32x4 rz[8], ni[4], nh[4];
    #pragma unroll
    for (int t = 0; t < 8; ++t) rz[t] = (f32x4){0.f, 0.f, 0.f, 0.f};
    #pragma unroll
    for (int t = 0; t < 4; ++t) {
        ni[t] = (f32x4){0.f, 0.f, 0.f, 0.f};
        nh[t] = (f32x4){0.f, 0.f, 0.f, 0.f};
    }

    #pragma unroll
    for (int ck = 0; ck < 2; ++ck) {
        short8 mhi, mlo, hhi, hlo;
        {
            float xv[8];
            f4pair_to8(am[ck * 2], am[ck * 2 + 1], xv);
            split8(xv, mhi, mlo);
            f4pair_to8(ah[ck * 2], ah[ck * 2 + 1], xv);
            split8(xv, hhi, hlo);
        }
        const unsigned short* ih = wih_h + (size_t)(ck * 12) * 512 + lane * 8;
        const unsigned short* il = wih_l + (size_t)(ck * 12) * 512 + lane * 8;
        const unsigned short* hh = whh_h + (size_t)(ck * 12) * 512 + lane * 8;
        const unsigned short* hl = whh_l + (size_t)(ck * 12) * 512 + lane * 8;
        PRIO1();
        #pragma unroll
        for (int tn = 0; tn < 8; ++tn) {
            short8 bihh = *(const short8*)(ih + tn * 512);
            short8 bihl = *(const short8*)(il + tn * 512);
            short8 bhhh = *(const short8*)(hh + tn * 512);
            short8 bhhl = *(const short8*)(hl + tn * 512);
            rz[tn] = __builtin_amdgcn_mfma_f32_16x16x32_bf16(mhi, bihh, rz[tn], 0, 0, 0);
            rz[tn] = __builtin_amdgcn_mfma_f32_16x16x32_bf16(mhi, bihl, rz[tn], 0, 0, 0);
            rz[tn] = __builtin_amdgcn_mfma_f32_16x16x32_bf16(mlo, bihh, rz[tn], 0, 0, 0);
            rz[tn] = __builtin_amdgcn_mfma_f32_16x16x32_bf16(hhi, bhhh, rz[tn], 0, 0, 0);
            rz[tn] = __builtin_amdgcn_mfma_f32_16x16x32_bf16(hhi, bhhl, rz[tn], 0, 0, 0);
            rz[tn] = __builtin_amdgcn_mfma_f32_16x16x32_bf16(hlo, bhhh, rz[tn], 0, 0, 0);
        }
        #pragma unroll
        for (int tn = 8; tn < 12; ++tn) {
            short8 bihh = *(const short8*)(ih + tn * 512);
            short8 bihl = *(const short8*)(il + tn * 512);
            short8 bhhh = *(const short8*)(hh + tn * 512);
            short8 bhhl = *(const short8*)(hl + tn * 512);
            ni[tn - 8] = __builtin_amdgcn_mfma_f32_16x16x32_bf16(mhi, bihh, ni[tn - 8], 0, 0, 0);
            ni[tn - 8] = __builtin_amdgcn_mfma_f32_16x16x32_bf16(mhi, bihl, ni[tn - 8], 0, 0, 0);
            ni[tn - 8] = __builtin_amdgcn_mfma_f32_16x16x32_bf16(mlo, bihh, ni[tn - 8], 0, 0, 0);
            nh[tn - 8] = __builtin_amdgcn_mfma_f32_16x16x32_bf16(hhi, bhhh, nh[tn - 8], 0, 0, 0);
            nh[tn - 8] = __builtin_amdgcn_mfma_f32_16x16x32_bf16(hhi, bhhl, nh[tn - 8], 0, 0, 0);
            nh[tn - 8] = __builtin_amdgcn_mfma_f32_16x16x32_bf16(hlo, bhhh, nh[tn - 8], 0, 0, 0);
        }
        PRIO0();
    }

    #pragma unroll
    for (int rr = 0; rr < 4; ++rr) {
        int rowl = wv * 16 + quad * 4 + rr;
        int grow = base + rowl;
        bool ok = grow < count;
        #pragma unroll
        for (int t = 0; t < 4; ++t) {
            int g = t * 16 + col;
            float rv = sigm(rz[t][rr] + bsr[t]);
            float zv = sigm(rz[4 + t][rr] + bsz[t]);
            float nv = tanh_f(ni[t][rr] + bin_[t] + rv * (nh[t][rr] + bhn[t]));
            if (ok) {
                float ho = Hs[rowl][g];
                hst[(size_t)grow * 64 + g] = (1.f - zv) * nv + zv * ho;
            }
            if (grow < nzero) nm[(size_t)grow * 64 + g] = 0.f;
        }
    }
}

// ---------- readout (unchanged) ----------
__global__ __launch_bounds__(256, 3)
void k_readout(const float* __restrict__ vh,
               const float* __restrict__ w1t, const float* __restrict__ b1,
               const float* __restrict__ w2t, const float* __restrict__ b2,
               const float* __restrict__ w3, const float* __restrict__ b3,
               float* __restrict__ out)
{
    __shared__ float H[HRDIM][64];
    const int lane = threadIdx.x & 63;
    const int wv   = __builtin_amdgcn_readfirstlane(threadIdx.x >> 6);
    const int n0 = blockIdx.x * 64 + lane;
    const int n  = n0 < NN ? n0 : NN - 1;
    const float4* px = (const float4*)(vh + (size_t)n * 64);

    const int j1 = 32 * wv;
    float acc[32];
    #pragma unroll
    for (int j = 0; j < 32; ++j) acc[j] = b1[j1 + j];
    #pragma unroll 4
    for (int q = 0; q < 16; ++q) {
        float4 x4 = px[q];
        const float* wa = w1t + (4 * q + 0) * HRDIM + j1;
        const float* wb = w1t + (4 * q + 1) * HRDIM + j1;
        const float* wc = w1t + (4 * q + 2) * HRDIM + j1;
        const float* wd = w1t + (4 * q + 3) * HRDIM + j1;
        #pragma unroll
        for (int j = 0; j < 32; ++j) {
            acc[j] = fmaf(wa[j], x4.x, acc[j]);
            acc[j] = fmaf(wb[j], x4.y, acc[j]);
            acc[j] = fmaf(wc[j], x4.z, acc[j]);
            acc[j] = fmaf(wd[j], x4.w, acc[j]);
        }
    }
    #pragma unroll
    for (int j = 0; j < 32; ++j) H[j1 + j][lane] = fmaxf(acc[j], 0.f);
    __syncthreads();

    #pragma unroll
    for (int j = 0; j < 32; ++j) acc[j] = b2[j1 + j];
    #pragma unroll 4
    for (int k = 0; k < HRDIM; ++k) {
        float xk = H[k][lane];
        const float* wr = w2t + k * HRDIM + j1;
        #pragma unroll
        for (int j = 0; j < 32; ++j)
            acc[j] = fmaf(wr[j], xk, acc[j]);
    }
    __syncthreads();
    #pragma unroll
    for (int j = 0; j < 32; ++j) H[j1 + j][lane] = fmaxf(acc[j], 0.f);
    __syncthreads();

    if (wv == 0 && n0 < NN) {
        float l0 = b3[0], l1 = b3[1];
        #pragma unroll 8
        for (int k = 0; k < HRDIM; ++k) {
            float hk = H[k][lane];
            l0 = fmaf(w3[k],         hk, l0);
            l1 = fmaf(w3[HRDIM + k], hk, l1);
        }
        float mx = fmaxf(l0, l1);
        float e0 = __expf(l0 - mx), e1 = __expf(l1 - mx);
        float inv = 1.f / (e0 + e1);
        out[2 * n + 0] = e0 * inv;
        out[2 * n + 1] = e1 * inv;
    }
}

// ---------- host ----------
extern "C" void kernel_launch(void* const* d_in, const int* in_sizes, int n_in,
                              void* d_out, int out_size, void* d_ws, size_t ws_size,
                              hipStream_t stream)
{
    float* var_h = (float*)d_ws;
    float* fac_h = var_h + 640000;
    float* nm    = fac_h + 5120000;
    float* ro_t  = nm + 5120000;            // 24,576 f32
    float* bsum  = ro_t + 24576;            // 384 f32 (2 x 192)
    unsigned short* pk = (unsigned short*)(bsum + 384); // 278,528 shorts

    const int*   f2v_row  = (const int*)d_in[0];
    const int*   f2v_col  = (const int*)d_in[1];
    const int*   v2f_row  = (const int*)d_in[2];
    const int*   v2f_col  = (const int*)d_in[3];
    const float* f2v_feat = (const float*)d_in[4];
    const float* v2f_feat = (const float*)d_in[5];
    const float* W[26];
    for (int j = 0; j < 26; ++j) W[j] = (const float*)d_in[6 + j];
    (void)f2v_row; (void)v2f_col;

    TArgs ta;
    float* T[NTR];
    {
        const float* src[NTR] = { W[20], W[22] };
        int R[NTR] = { HRDIM, HRDIM };
        int C[NTR] = { SDIM, HRDIM };
        size_t off = 0;
        for (int t = 0; t < NTR; ++t) {
            ta.src[t] = src[t]; ta.R[t] = R[t]; ta.C[t] = C[t];
            T[t] = ro_t + off; ta.dst[t] = T[t];
            off += (size_t)R[t] * C[t];
        }
    }
    unsigned short* P[12];
    unsigned short* G[8];
    {
        size_t off = 0;
        int esz[3] = { 20480, 16384, 8192 };
        for (int d = 0; d < 2; ++d)
            for (int m = 0; m < 3; ++m) {
                P[d * 6 + m * 2 + 0] = pk + off; off += esz[m];
                P[d * 6 + m * 2 + 1] = pk + off; off += esz[m];
            }
        for (int t = 0; t < 8; ++t) { G[t] = pk + off; off += 12288; }
    }
    PArgs pa;
    {
        const float* src[NPK] = { W[0], W[2], W[4], W[6], W[8], W[10],
                                  W[12], W[13], W[16], W[17] };
        int N[NPK]  = { HMDIM, HMDIM, SDIM,  HMDIM, HMDIM, SDIM,  192, 192, 192, 192 };
        int K[NPK]  = { KIN,   HMDIM, HMDIM, KIN,   HMDIM, HMDIM, SDIM, SDIM, SDIM, SDIM };
        int CK[NPK] = { 5,     4,     4,     5,     4,     4,     2,   2,   2,   2 };
        unsigned short* hi[NPK] = { P[0], P[2], P[4], P[6], P[8], P[10],
                                    G[0], G[2], G[4], G[6] };
        unsigned short* lo[NPK] = { P[1], P[3], P[5], P[7], P[9], P[11],
                                    G[1], G[3], G[5], G[7] };
        for (int t = 0; t < NPK; ++t) {
            pa.src[t] = src[t]; pa.N[t] = N[t]; pa.K[t] = K[t]; pa.CK[t] = CK[t];
            pa.hi[t] = hi[t];   pa.lo[t] = lo[t];
        }
    }
    k_transpose<<<NTR, 256, 0, stream>>>(ta);
    k_pack<<<NPK, 256, 0, stream>>>(pa);
    k_bsum<<<1, 256, 0, stream>>>(W[14], W[15], bsum, W[18], W[19], bsum + 192);
    k_zero<<<512, 256, 0, stream>>>(var_h, 640000 + 5120000 + 5120000);

    for (int s = 0; s < NSTEPS; ++s) {
        // fac -> var messages into nm[node] (atomic scatter); var GRU reads
        // nm and re-zeroes rows [0,NN) for the next step's atomics.
        k_edge_mfma<<<NE / 64, 256, 0, stream>>>(
            fac_h, var_h, f2v_col, f2v_feat,
            P[0], P[1], P[2], P[3], P[4], P[5],
            W[1], W[3], W[5], nm);
        k_gru_mfma<<<(NN + 63) / 64, 256, 0, stream>>>(
            nm, G[0], G[1], G[2], G[3], bsum, W[14], W[15], var_h, NN, NN);
        // var -> fac messages + fac GRU, fused (factor messages stay in LDS;
        // nm untouched in the factor region).
        k_edge_gru_fused<<<NE / 64, 256, 0, stream>>>(
            var_h, fac_h, v2f_row, v2f_feat,
            P[6], P[7], P[8], P[9], P[10], P[11],
            W[7], W[9], W[11],
            G[4], G[5], G[6], G[7], bsum + 192, W[18], W[19]);
    }
    k_readout<<<(NN + 63) / 64, 256, 0, stream>>>(
        var_h, T[0], W[21], T[1], W[23], W[24], W[25],
        (float*)d_out);
}

// Round 17
// 906.246 us; speedup vs baseline: 1.0874x; 1.0275x over previous
//
#include <hip/hip_runtime.h>
#include <hip/hip_bf16.h>

// Problem constants (fixed by reference setup)
#define NN     10000      // variable nodes
#define NF     80000      // factors
#define NE     160000     // directed edges per direction
#define SDIM   64         // state dim
#define HMDIM  128        // hidden (message MLP)
#define HRDIM  128        // hidden (readout)
#define KIN    136        // 2*S + 8
#define NSTEPS 5

static_assert(NE % 64 == 0, "edge grid exact");

typedef __attribute__((ext_vector_type(8))) short short8;   // 8 bf16 = 4 VGPRs
typedef __attribute__((ext_vector_type(4))) float f32x4;    // MFMA C/D

// ---------- helpers ----------
static __device__ __forceinline__ float bf2f(unsigned short u) {
    return __uint_as_float(((unsigned int)u) << 16);
}
// R4: pure fp16 fails absmax; 3-MFMA bf16 hi/lo is the numerics floor.
// R9: direct-global B for the edge MLP is latency-bound; staged-LDS only.
// R12: single-barrier phases + gl stride pad both regressed.
// R13/R14: fused layer-3 staging loop needed its trailing barrier (race).
// R15/R16: f32 H tile + split-on-read: 969 -> 931us, bit-identical numerics.
// R17: merge 4 setup kernels into 1 (saves 3 launch gaps); vectorize the
// fused combine phase (float4 gl/fstate/bias access, same arithmetic).
static __device__ __forceinline__ unsigned short f2bf(float f) {
    __hip_bfloat16 h = __float2bfloat16(f);
    unsigned short u;
    __builtin_memcpy(&u, &h, 2);
    return u;
}
static __device__ __forceinline__ float sigm(float x) {
    x = fminf(fmaxf(x, -30.f), 30.f);
    return 1.f / (1.f + __expf(-x));
}
static __device__ __forceinline__ float tanh_f(float x) {
    x = fminf(fmaxf(x, -15.f), 15.f);
    float t = __expf(2.f * x);
    return (t - 1.f) / (t + 1.f);
}
// split f32 -> bf16 hi + bf16 lo (x ~= hi + lo, ~16 mantissa bits kept)
static __device__ __forceinline__ void split8(const float* x, short8& hi, short8& lo) {
    #pragma unroll
    for (int i = 0; i < 8; ++i) {
        unsigned short h = f2bf(x[i]);
        hi[i] = (short)h;
        lo[i] = (short)f2bf(x[i] - bf2f(h));
    }
}
static __device__ __forceinline__ void f4pair_to8(float4 a, float4 b, float* xv) {
    xv[0]=a.x; xv[1]=a.y; xv[2]=a.z; xv[3]=a.w;
    xv[4]=b.x; xv[5]=b.y; xv[6]=b.z; xv[7]=b.w;
}
// async global->LDS DMA, 16B per lane, no VGPR round-trip (tracked by vmcnt)
static __device__ __forceinline__ void dma16(const unsigned short* g, unsigned short* l) {
    __builtin_amdgcn_global_load_lds(
        (const __attribute__((address_space(1))) void*)g,
        (__attribute__((address_space(3))) void*)l,
        16, 0, 0);
}

#define LGKM0() asm volatile("s_waitcnt lgkmcnt(0)" ::: "memory")
#define VMC2()  asm volatile("s_waitcnt vmcnt(2)"   ::: "memory")
#define VMC0()  asm volatile("s_waitcnt vmcnt(0)"   ::: "memory")
#define SBAR()  __builtin_amdgcn_s_barrier()
#define SCHED0() __builtin_amdgcn_sched_barrier(0)
#define PRIO1() __builtin_amdgcn_s_setprio(1)
#define PRIO0() __builtin_amdgcn_s_setprio(0)

// ---------- merged setup kernel ----------
// blocks [0,NPK): weight pack | [NPK,NPK+NTR): transpose | NPK+NTR: bsum |
// [NPK+NTR+1, NPK+NTR+1+NZB): zero. All outputs disjoint; math identical
// to the former 4 kernels; saves 3 launch gaps per measured call.
#define NPK 10
#define NTR 2
#define NZB 512
struct SArgs {
    // pack
    const float*    psrc[NPK];
    unsigned short* phi[NPK];
    unsigned short* plo[NPK];
    int             N[NPK], K[NPK], CK[NPK];
    // transpose
    const float* tsrc[NTR];
    float*       tdst[NTR];
    int          R[NTR], C[NTR];
    // bsum
    const float* bih0; const float* bhh0; float* o0;
    const float* bih1; const float* bhh1; float* o1;
    // zero
    float* zp; int zn;
};
__global__ void k_setup(SArgs a) {
    const int b = blockIdx.x;
    if (b < NPK) {
        const float* s = a.psrc[b];
        unsigned short* ph = a.phi[b];
        unsigned short* pl = a.plo[b];
        const int N = a.N[b], K = a.K[b], CK = a.CK[b];
        const int NT = N >> 4;
        const int total = NT * CK * 512;
        for (int i = threadIdx.x; i < total; i += blockDim.x) {
            int j    = i & 7;
            int ln   = (i >> 3) & 63;
            int tile = i >> 9;
            int tn   = tile % NT;
            int ck   = tile / NT;
            int k = ck * 32 + ((ln >> 4) * 8) + j;
            int n = tn * 16 + (ln & 15);
            float f = (k < K) ? s[n * K + k] : 0.f;
            unsigned short h = f2bf(f);
            ph[i] = h;
            pl[i] = f2bf(f - bf2f(h));
        }
    } else if (b < NPK + NTR) {
        const int t = b - NPK;
        const float* s = a.tsrc[t];
        float* d = a.tdst[t];
        const int R = a.R[t], C = a.C[t], n = R * C;
        for (int i = threadIdx.x; i < n; i += blockDim.x) {
            int r = i / C, c = i % C;
            d[c * R + r] = s[i];
        }
    } else if (b == NPK + NTR) {
        int i = threadIdx.x;
        if (i < 192) { a.o0[i] = a.bih0[i] + a.bhh0[i]; a.o1[i] = a.bih1[i] + a.bhh1[i]; }
    } else {
        const int zb = b - (NPK + NTR + 1);
        int i = zb * 256 + threadIdx.x;
        const int stride = NZB * 256;
        for (; i < a.zn; i += stride) a.zp[i] = 0.f;
    }
}

// ---- half-phase B staging: 4KB hi + 4KB lo per half-phase, dbuf 16KB ----
#define STAGE(buf, sh, sl) do {                                            \
    const int u0_ = wv * 2;                                                \
    _Pragma("unroll")                                                      \
    for (int k_ = 0; k_ < 2; ++k_) {                                       \
        const int u_ = u0_ + k_;                                           \
        const unsigned short* s_ = (u_ < 4 ? (sh) : (sl)) + (u_ & 3) * 512;\
        unsigned short* d_ = (u_ < 4 ? &BH[buf][0] : &BL[buf][0]) + (u_ & 3) * 512; \
        dma16(s_ + lane * 8, d_);                                          \
    }                                                                      \
} while (0)

// read 8 floats from Hf row m0 at column c0, split to bf16 hi/lo frags
#define A_FROM_HF(dsthi, dstlo, c0_) do {                                  \
    float xv_[8];                                                          \
    *(float4*)&xv_[0] = *(const float4*)(&Hf[m0][(c0_)]);                  \
    *(float4*)&xv_[4] = *(const float4*)(&Hf[m0][(c0_) + 4]);              \
    split8(xv_, dsthi, dstlo);                                             \
} while (0)

// ---------- f2v MFMA edge MLP + atomic scatter ----------
__global__ __launch_bounds__(256, 3)
void k_edge_mfma(const float* __restrict__ hrow, const float* __restrict__ hcol,
                 const int* __restrict__ cols,
                 const float* __restrict__ feat,
                 const unsigned short* __restrict__ w1h, const unsigned short* __restrict__ w1l,
                 const unsigned short* __restrict__ w2h, const unsigned short* __restrict__ w2l,
                 const unsigned short* __restrict__ w3h, const unsigned short* __restrict__ w3l,
                 const float* __restrict__ b1, const float* __restrict__ b2,
                 const float* __restrict__ b3,
                 float* __restrict__ nm)
{
    __shared__ __align__(16) float Hf[64][132];             // 33.8 KB (f32 H)
    __shared__ __align__(16) unsigned short BH[2][2048];    // 8 KB (dbuf hi)
    __shared__ __align__(16) unsigned short BL[2][2048];    // 8 KB (dbuf lo)
    const int lane = threadIdx.x & 63;
    const int wv   = threadIdx.x >> 6;        // 0..3
    const int quad = lane >> 4;               // 0..3
    const int col  = lane & 15;

    const int e0 = blockIdx.x * 64 + wv * 16 + col;
    const int r0 = e0 >> 1;                   // f2v rows = fidx = e/2
    const int c0 = cols[e0];

    float4 gR[4], gC[4], gFr, gFc;
    {
        const float4* pr = (const float4*)(hrow + (size_t)r0 * 64);
        const float4* pc = (const float4*)(hcol + (size_t)c0 * 64);
        gR[0] = pr[quad * 2];     gR[1] = pr[quad * 2 + 1];
        gR[2] = pr[8 + quad * 2]; gR[3] = pr[8 + quad * 2 + 1];
        gC[0] = pc[quad * 2];     gC[1] = pc[quad * 2 + 1];
        gC[2] = pc[8 + quad * 2]; gC[3] = pc[8 + quad * 2 + 1];
        gFr = *(const float4*)(feat + (size_t)r0 * 4);
        gFc = *(const float4*)(feat + (size_t)c0 * 4);
    }
    int cc[4];
    #pragma unroll
    for (int rr = 0; rr < 4; ++rr)
        cc[rr] = cols[blockIdx.x * 64 + wv * 16 + quad * 4 + rr];

    float b1v[8], b2v[8], b3v[4];
    #pragma unroll
    for (int t = 0; t < 8; ++t) { b1v[t] = b1[t * 16 + col]; b2v[t] = b2[t * 16 + col]; }
    #pragma unroll
    for (int t = 0; t < 4; ++t) b3v[t] = b3[t * 16 + col];

    VMC0(); SCHED0();
    STAGE(0, w1h, w1l);

    f32x4 acc[8];
    #pragma unroll
    for (int t = 0; t < 8; ++t) acc[t] = (f32x4){0.f, 0.f, 0.f, 0.f};

    short8 ahi, alo;
    #pragma unroll
    for (int hp = 0; hp < 10; ++hp) {
        {
            const unsigned short* nh; const unsigned short* nl;
            if (hp < 9) { nh = w1h + (hp + 1) * 2048; nl = w1l + (hp + 1) * 2048; }
            else        { nh = w2h;                   nl = w2l; }
            STAGE((hp + 1) & 1, nh, nl);
        }
        if ((hp & 1) == 0) {
            const int ck = hp >> 1;
            float xv[8];
            if (ck < 2)      f4pair_to8(gR[ck * 2], gR[ck * 2 + 1], xv);
            else if (ck < 4) f4pair_to8(gC[(ck - 2) * 2], gC[(ck - 2) * 2 + 1], xv);
            else if (quad == 0) f4pair_to8(gFr, gFc, xv);
            else {
                #pragma unroll
                for (int i = 0; i < 8; ++i) xv[i] = 0.f;
            }
            split8(xv, ahi, alo);
        }
        VMC2(); LGKM0(); SBAR(); SCHED0();
        {
            const unsigned short* bh = &BH[hp & 1][0];
            const unsigned short* bl = &BL[hp & 1][0];
            #pragma unroll
            for (int t = 0; t < 4; ++t) {
                const int tn = (hp & 1) * 4 + t;
                short8 bhi = *(const short8*)(bh + t * 512 + lane * 8);
                short8 blo = *(const short8*)(bl + t * 512 + lane * 8);
                acc[tn] = __builtin_amdgcn_mfma_f32_16x16x32_bf16(ahi, bhi, acc[tn], 0, 0, 0);
                acc[tn] = __builtin_amdgcn_mfma_f32_16x16x32_bf16(ahi, blo, acc[tn], 0, 0, 0);
                acc[tn] = __builtin_amdgcn_mfma_f32_16x16x32_bf16(alo, bhi, acc[tn], 0, 0, 0);
            }
        }
        LGKM0(); SBAR(); SCHED0();
    }
    // epilogue 1: bias + relu -> Hf (f32, wave-private rows; no converts)
    #pragma unroll
    for (int tn = 0; tn < 8; ++tn)
        #pragma unroll
        for (int rr = 0; rr < 4; ++rr)
            Hf[wv * 16 + quad * 4 + rr][tn * 16 + col] =
                fmaxf(acc[tn][rr] + b1v[tn], 0.f);

    #pragma unroll
    for (int t = 0; t < 8; ++t) acc[t] = (f32x4){0.f, 0.f, 0.f, 0.f};
    const int m0 = wv * 16 + col;
    #pragma unroll
    for (int h2 = 0; h2 < 8; ++h2) {
        const int hp = 10 + h2;
        {
            const unsigned short* nh; const unsigned short* nl;
            if (h2 < 7) { nh = w2h + (h2 + 1) * 2048; nl = w2l + (h2 + 1) * 2048; }
            else        { nh = w3h;                   nl = w3l; }
            STAGE((hp + 1) & 1, nh, nl);
        }
        if ((h2 & 1) == 0) {
            const int ck = h2 >> 1;
            A_FROM_HF(ahi, alo, ck * 32 + quad * 8);
        }
        VMC2(); LGKM0(); SBAR(); SCHED0();
        {
            const unsigned short* bh = &BH[hp & 1][0];
            const unsigned short* bl = &BL[hp & 1][0];
            #pragma unroll
            for (int t = 0; t < 4; ++t) {
                const int tn = (h2 & 1) * 4 + t;
                short8 bhi = *(const short8*)(bh + t * 512 + lane * 8);
                short8 blo = *(const short8*)(bl + t * 512 + lane * 8);
                acc[tn] = __builtin_amdgcn_mfma_f32_16x16x32_bf16(ahi, bhi, acc[tn], 0, 0, 0);
                acc[tn] = __builtin_amdgcn_mfma_f32_16x16x32_bf16(ahi, blo, acc[tn], 0, 0, 0);
                acc[tn] = __builtin_amdgcn_mfma_f32_16x16x32_bf16(alo, bhi, acc[tn], 0, 0, 0);
            }
        }
        LGKM0(); SBAR(); SCHED0();
    }
    // epilogue 2 (f32, wave-private rows)
    #pragma unroll
    for (int tn = 0; tn < 8; ++tn)
        #pragma unroll
        for (int rr = 0; rr < 4; ++rr)
            Hf[wv * 16 + quad * 4 + rr][tn * 16 + col] =
                fmaxf(acc[tn][rr] + b2v[tn], 0.f);

    f32x4 a3[4];
    #pragma unroll
    for (int t = 0; t < 4; ++t) a3[t] = (f32x4){0.f, 0.f, 0.f, 0.f};
    #pragma unroll
    for (int h3 = 0; h3 < 4; ++h3) {
        const int hp = 18 + h3;
        if (h3 < 3) STAGE((hp + 1) & 1, w3h + (h3 + 1) * 2048, w3l + (h3 + 1) * 2048);
        short8 a3h, a3l;
        A_FROM_HF(a3h, a3l, h3 * 32 + quad * 8);
        if (h3 < 3) { VMC2(); } else { VMC0(); }
        LGKM0(); SBAR(); SCHED0();
        {
            const unsigned short* bh = &BH[hp & 1][0];
            const unsigned short* bl = &BL[hp & 1][0];
            #pragma unroll
            for (int t = 0; t < 4; ++t) {
                short8 bhi = *(const short8*)(bh + t * 512 + lane * 8);
                short8 blo = *(const short8*)(bl + t * 512 + lane * 8);
                a3[t] = __builtin_amdgcn_mfma_f32_16x16x32_bf16(a3h, bhi, a3[t], 0, 0, 0);
                a3[t] = __builtin_amdgcn_mfma_f32_16x16x32_bf16(a3h, blo, a3[t], 0, 0, 0);
                a3[t] = __builtin_amdgcn_mfma_f32_16x16x32_bf16(a3l, bhi, a3[t], 0, 0, 0);
            }
        }
        if (h3 < 3) { LGKM0(); SBAR(); SCHED0(); }
    }

    #pragma unroll
    for (int tn = 0; tn < 4; ++tn) {
        float bias = b3v[tn];
        #pragma unroll
        for (int rr = 0; rr < 4; ++rr)
            atomicAdd(&nm[(size_t)cc[rr] * 64 + tn * 16 + col], a3[tn][rr] + bias);
    }
}

// ---------- FUSED v2f edge MLP + fac GRU ----------
__global__ __launch_bounds__(256, 3)
void k_edge_gru_fused(const float* __restrict__ hrow, float* fstate,
                      const int* __restrict__ rows,
                      const float* __restrict__ feat,
                      const unsigned short* __restrict__ w1h, const unsigned short* __restrict__ w1l,
                      const unsigned short* __restrict__ w2h, const unsigned short* __restrict__ w2l,
                      const unsigned short* __restrict__ w3h, const unsigned short* __restrict__ w3l,
                      const float* __restrict__ b1, const float* __restrict__ b2,
                      const float* __restrict__ b3,
                      const unsigned short* __restrict__ gih_h, const unsigned short* __restrict__ gih_l,
                      const unsigned short* __restrict__ ghh_h, const unsigned short* __restrict__ ghh_l,
                      const float* __restrict__ bsum, const float* __restrict__ bih,
                      const float* __restrict__ bhh)
{
    // 51200B arena. Phase-1: Hf f32 [0,33792) | BH [33792,41984) |
    // BL [41984,50176). Phase-2 overlays (behind barrier A): nmL = [0,8704)
    // float[32][68]; gl = [8704,41984) float[32][260].
    __shared__ __align__(16) unsigned char SM[51200];
    float (*Hf)[132] = (float(*)[132])(SM);
    unsigned short (*BH)[2048] = (unsigned short(*)[2048])(SM + 33792);
    unsigned short (*BL)[2048] = (unsigned short(*)[2048])(SM + 41984);
    float (*nmL)[68]  = (float(*)[68])(SM);
    float (*gl)[260]  = (float(*)[260])(SM + 8704);

    const int lane = threadIdx.x & 63;
    const int wv   = threadIdx.x >> 6;        // 0..3
    const int quad = lane >> 4;               // 0..3
    const int col  = lane & 15;

    const int e0 = blockIdx.x * 64 + wv * 16 + col;
    const int r0 = rows[e0];                  // variable endpoint
    const int c0 = e0 >> 1;                   // v2f cols = fidx = e/2

    float4 gR[4], gC[4], gFr, gFc;
    {
        const float4* pr = (const float4*)(hrow + (size_t)r0 * 64);
        const float4* pc = (const float4*)(fstate + (size_t)c0 * 64);
        gR[0] = pr[quad * 2];     gR[1] = pr[quad * 2 + 1];
        gR[2] = pr[8 + quad * 2]; gR[3] = pr[8 + quad * 2 + 1];
        gC[0] = pc[quad * 2];     gC[1] = pc[quad * 2 + 1];
        gC[2] = pc[8 + quad * 2]; gC[3] = pc[8 + quad * 2 + 1];
        gFr = *(const float4*)(feat + (size_t)r0 * 4);
        gFc = *(const float4*)(feat + (size_t)c0 * 4);
    }
    float b1v[8], b2v[8], b3v[4];
    #pragma unroll
    for (int t = 0; t < 8; ++t) { b1v[t] = b1[t * 16 + col]; b2v[t] = b2[t * 16 + col]; }
    #pragma unroll
    for (int t = 0; t < 4; ++t) b3v[t] = b3[t * 16 + col];

    VMC0(); SCHED0();
    STAGE(0, w1h, w1l);

    f32x4 acc[8];
    #pragma unroll
    for (int t = 0; t < 8; ++t) acc[t] = (f32x4){0.f, 0.f, 0.f, 0.f};

    short8 ahi, alo;
    #pragma unroll
    for (int hp = 0; hp < 10; ++hp) {
        {
            const unsigned short* nh; const unsigned short* nl;
            if (hp < 9) { nh = w1h + (hp + 1) * 2048; nl = w1l + (hp + 1) * 2048; }
            else        { nh = w2h;                   nl = w2l; }
            STAGE((hp + 1) & 1, nh, nl);
        }
        if ((hp & 1) == 0) {
            const int ck = hp >> 1;
            float xv[8];
            if (ck < 2)      f4pair_to8(gR[ck * 2], gR[ck * 2 + 1], xv);
            else if (ck < 4) f4pair_to8(gC[(ck - 2) * 2], gC[(ck - 2) * 2 + 1], xv);
            else if (quad == 0) f4pair_to8(gFr, gFc, xv);
            else {
                #pragma unroll
                for (int i = 0; i < 8; ++i) xv[i] = 0.f;
            }
            split8(xv, ahi, alo);
        }
        VMC2(); LGKM0(); SBAR(); SCHED0();
        {
            const unsigned short* bh = &BH[hp & 1][0];
            const unsigned short* bl = &BL[hp & 1][0];
            #pragma unroll
            for (int t = 0; t < 4; ++t) {
                const int tn = (hp & 1) * 4 + t;
                short8 bhi = *(const short8*)(bh + t * 512 + lane * 8);
                short8 blo = *(const short8*)(bl + t * 512 + lane * 8);
                acc[tn] = __builtin_amdgcn_mfma_f32_16x16x32_bf16(ahi, bhi, acc[tn], 0, 0, 0);
                acc[tn] = __builtin_amdgcn_mfma_f32_16x16x32_bf16(ahi, blo, acc[tn], 0, 0, 0);
                acc[tn] = __builtin_amdgcn_mfma_f32_16x16x32_bf16(alo, bhi, acc[tn], 0, 0, 0);
            }
        }
        LGKM0(); SBAR(); SCHED0();
    }
    #pragma unroll
    for (int tn = 0; tn < 8; ++tn)
        #pragma unroll
        for (int rr = 0; rr < 4; ++rr)
            Hf[wv * 16 + quad * 4 + rr][tn * 16 + col] =
                fmaxf(acc[tn][rr] + b1v[tn], 0.f);

    #pragma unroll
    for (int t = 0; t < 8; ++t) acc[t] = (f32x4){0.f, 0.f, 0.f, 0.f};
    const int m0 = wv * 16 + col;
    #pragma unroll
    for (int h2 = 0; h2 < 8; ++h2) {
        const int hp = 10 + h2;
        {
            const unsigned short* nh; const unsigned short* nl;
            if (h2 < 7) { nh = w2h + (h2 + 1) * 2048; nl = w2l + (h2 + 1) * 2048; }
            else        { nh = w3h;                   nl = w3l; }
            STAGE((hp + 1) & 1, nh, nl);
        }
        if ((h2 & 1) == 0) {
            const int ck = h2 >> 1;
            A_FROM_HF(ahi, alo, ck * 32 + quad * 8);
        }
        VMC2(); LGKM0(); SBAR(); SCHED0();
        {
            const unsigned short* bh = &BH[hp & 1][0];
            const unsigned short* bl = &BL[hp & 1][0];
            #pragma unroll
            for (int t = 0; t < 4; ++t) {
                const int tn = (h2 & 1) * 4 + t;
                short8 bhi = *(const short8*)(bh + t * 512 + lane * 8);
                short8 blo = *(const short8*)(bl + t * 512 + lane * 8);
                acc[tn] = __builtin_amdgcn_mfma_f32_16x16x32_bf16(ahi, bhi, acc[tn], 0, 0, 0);
                acc[tn] = __builtin_amdgcn_mfma_f32_16x16x32_bf16(ahi, blo, acc[tn], 0, 0, 0);
                acc[tn] = __builtin_amdgcn_mfma_f32_16x16x32_bf16(alo, bhi, acc[tn], 0, 0, 0);
            }
        }
        LGKM0(); SBAR(); SCHED0();
    }
    #pragma unroll
    for (int tn = 0; tn < 8; ++tn)
        #pragma unroll
        for (int rr = 0; rr < 4; ++rr)
            Hf[wv * 16 + quad * 4 + rr][tn * 16 + col] =
                fmaxf(acc[tn][rr] + b2v[tn], 0.f);

    f32x4 a3[4];
    #pragma unroll
    for (int t = 0; t < 4; ++t) a3[t] = (f32x4){0.f, 0.f, 0.f, 0.f};
    #pragma unroll
    for (int h3 = 0; h3 < 4; ++h3) {
        const int hp = 18 + h3;
        if (h3 < 3) STAGE((hp + 1) & 1, w3h + (h3 + 1) * 2048, w3l + (h3 + 1) * 2048);
        short8 a3h, a3l;
        A_FROM_HF(a3h, a3l, h3 * 32 + quad * 8);
        if (h3 < 3) { VMC2(); } else { VMC0(); }
        LGKM0(); SBAR(); SCHED0();
        {
            const unsigned short* bh = &BH[hp & 1][0];
            const unsigned short* bl = &BL[hp & 1][0];
            #pragma unroll
            for (int t = 0; t < 4; ++t) {
                short8 bhi = *(const short8*)(bh + t * 512 + lane * 8);
                short8 blo = *(const short8*)(bl + t * 512 + lane * 8);
                a3[t] = __builtin_amdgcn_mfma_f32_16x16x32_bf16(a3h, bhi, a3[t], 0, 0, 0);
                a3[t] = __builtin_amdgcn_mfma_f32_16x16x32_bf16(a3h, blo, a3[t], 0, 0, 0);
                a3[t] = __builtin_amdgcn_mfma_f32_16x16x32_bf16(a3l, bhi, a3[t], 0, 0, 0);
            }
        }
        // trailing barrier (R14 fix): next STAGE overwrites the buffer
        // these MFMAs read; keep waves separated.
        if (h3 < 3) { LGKM0(); SBAR(); SCHED0(); }
    }

    // ---- barrier A: every wave done with Hf/B reads -> overlays safe
    LGKM0(); SBAR(); SCHED0();

    // pairsum -> nmL (factor message tile, rows = local factor 0..31)
    {
        int lf0 = wv * 8 + quad * 2;
        #pragma unroll
        for (int tn = 0; tn < 4; ++tn) {
            float b2x = 2.f * b3v[tn];
            nmL[lf0][tn * 16 + col]     = a3[tn][0] + a3[tn][1] + b2x;
            nmL[lf0 + 1][tn * 16 + col] = a3[tn][2] + a3[tn][3] + b2x;
        }
    }
    LGKM0(); SBAR(); SCHED0();   // barrier B: nmL visible to all waves

    // ---- fused fac GRU: 32 factors, wave = (Mhalf mt, Nhalf half) ----
    const int fbase = blockIdx.x * 32;
    const int mt    = wv >> 1;             // 16-row M-tile
    const int half  = wv & 1;              // gate-tile half (6 of 12)
    const int hrow0 = fbase + mt * 16 + col;

    if (half == 0) {
        f32x4 rz6[6];
        #pragma unroll
        for (int i = 0; i < 6; ++i) rz6[i] = (f32x4){0.f, 0.f, 0.f, 0.f};
        #pragma unroll
        for (int ck = 0; ck < 2; ++ck) {
            short8 mhi, mlo, hhi, hlo;
            {
                float xv[8];
                *(float4*)&xv[0] = *(const float4*)(&nmL[mt * 16 + col][ck * 32 + quad * 8]);
                *(float4*)&xv[4] = *(const float4*)(&nmL[mt * 16 + col][ck * 32 + quad * 8 + 4]);
                split8(xv, mhi, mlo);
                const float* hp_ = fstate + (size_t)hrow0 * 64 + ck * 32 + quad * 8;
                *(float4*)&xv[0] = *(const float4*)(hp_);
                *(float4*)&xv[4] = *(const float4*)(hp_ + 4);
                split8(xv, hhi, hlo);
            }
            const unsigned short* ih = gih_h + (size_t)(ck * 12) * 512 + lane * 8;
            const unsigned short* il = gih_l + (size_t)(ck * 12) * 512 + lane * 8;
            const unsigned short* hh = ghh_h + (size_t)(ck * 12) * 512 + lane * 8;
            const unsigned short* hl = ghh_l + (size_t)(ck * 12) * 512 + lane * 8;
            #pragma unroll
            for (int i = 0; i < 6; ++i) {
                short8 bihh = *(const short8*)(ih + i * 512);
                short8 bihl = *(const short8*)(il + i * 512);
                short8 bhhh = *(const short8*)(hh + i * 512);
                short8 bhhl = *(const short8*)(hl + i * 512);
                rz6[i] = __builtin_amdgcn_mfma_f32_16x16x32_bf16(mhi, bihh, rz6[i], 0, 0, 0);
                rz6[i] = __builtin_amdgcn_mfma_f32_16x16x32_bf16(mhi, bihl, rz6[i], 0, 0, 0);
                rz6[i] = __builtin_amdgcn_mfma_f32_16x16x32_bf16(mlo, bihh, rz6[i], 0, 0, 0);
                rz6[i] = __builtin_amdgcn_mfma_f32_16x16x32_bf16(hhi, bhhh, rz6[i], 0, 0, 0);
                rz6[i] = __builtin_amdgcn_mfma_f32_16x16x32_bf16(hhi, bhhl, rz6[i], 0, 0, 0);
                rz6[i] = __builtin_amdgcn_mfma_f32_16x16x32_bf16(hlo, bhhh, rz6[i], 0, 0, 0);
            }
        }
        #pragma unroll
        for (int i = 0; i < 6; ++i)
            #pragma unroll
            for (int rr = 0; rr < 4; ++rr)
                gl[mt * 16 + quad * 4 + rr][i * 16 + col] = rz6[i][rr];
    } else {
        f32x4 rz2[2], niA[4], nhA[4];
        #pragma unroll
        for (int i = 0; i < 2; ++i) rz2[i] = (f32x4){0.f, 0.f, 0.f, 0.f};
        #pragma unroll
        for (int i = 0; i < 4; ++i) {
            niA[i] = (f32x4){0.f, 0.f, 0.f, 0.f};
            nhA[i] = (f32x4){0.f, 0.f, 0.f, 0.f};
        }
        #pragma unroll
        for (int ck = 0; ck < 2; ++ck) {
            short8 mhi, mlo, hhi, hlo;
            {
                float xv[8];
                *(float4*)&xv[0] = *(const float4*)(&nmL[mt * 16 + col][ck * 32 + quad * 8]);
                *(float4*)&xv[4] = *(const float4*)(&nmL[mt * 16 + col][ck * 32 + quad * 8 + 4]);
                split8(xv, mhi, mlo);
                const float* hp_ = fstate + (size_t)hrow0 * 64 + ck * 32 + quad * 8;
                *(float4*)&xv[0] = *(const float4*)(hp_);
                *(float4*)&xv[4] = *(const float4*)(hp_ + 4);
                split8(xv, hhi, hlo);
            }
            const unsigned short* ih = gih_h + (size_t)(ck * 12) * 512 + lane * 8;
            const unsigned short* il = gih_l + (size_t)(ck * 12) * 512 + lane * 8;
            const unsigned short* hh = ghh_h + (size_t)(ck * 12) * 512 + lane * 8;
            const unsigned short* hl = ghh_l + (size_t)(ck * 12) * 512 + lane * 8;
            #pragma unroll
            for (int i = 0; i < 2; ++i) {          // rz tiles 6,7
                const int tn = 6 + i;
                short8 bihh = *(const short8*)(ih + tn * 512);
                short8 bihl = *(const short8*)(il + tn * 512);
                short8 bhhh = *(const short8*)(hh + tn * 512);
                short8 bhhl = *(const short8*)(hl + tn * 512);
                rz2[i] = __builtin_amdgcn_mfma_f32_16x16x32_bf16(mhi, bihh, rz2[i], 0, 0, 0);
                rz2[i] = __builtin_amdgcn_mfma_f32_16x16x32_bf16(mhi, bihl, rz2[i], 0, 0, 0);
                rz2[i] = __builtin_amdgcn_mfma_f32_16x16x32_bf16(mlo, bihh, rz2[i], 0, 0, 0);
                rz2[i] = __builtin_amdgcn_mfma_f32_16x16x32_bf16(hhi, bhhh, rz2[i], 0, 0, 0);
                rz2[i] = __builtin_amdgcn_mfma_f32_16x16x32_bf16(hhi, bhhl, rz2[i], 0, 0, 0);
                rz2[i] = __builtin_amdgcn_mfma_f32_16x16x32_bf16(hlo, bhhh, rz2[i], 0, 0, 0);
            }
            #pragma unroll
            for (int i = 0; i < 4; ++i) {          // n tiles 8..11
                const int tn = 8 + i;
                short8 bihh = *(const short8*)(ih + tn * 512);
                short8 bihl = *(const short8*)(il + tn * 512);
                short8 bhhh = *(const short8*)(hh + tn * 512);
                short8 bhhl = *(const short8*)(hl + tn * 512);
                niA[i] = __builtin_amdgcn_mfma_f32_16x16x32_bf16(mhi, bihh, niA[i], 0, 0, 0);
                niA[i] = __builtin_amdgcn_mfma_f32_16x16x32_bf16(mhi, bihl, niA[i], 0, 0, 0);
                niA[i] = __builtin_amdgcn_mfma_f32_16x16x32_bf16(mlo, bihh, niA[i], 0, 0, 0);
                nhA[i] = __builtin_amdgcn_mfma_f32_16x16x32_bf16(hhi, bhhh, nhA[i], 0, 0, 0);
                nhA[i] = __builtin_amdgcn_mfma_f32_16x16x32_bf16(hhi, bhhl, nhA[i], 0, 0, 0);
                nhA[i] = __builtin_amdgcn_mfma_f32_16x16x32_bf16(hlo, bhhh, nhA[i], 0, 0, 0);
            }
        }
        #pragma unroll
        for (int rr = 0; rr < 4; ++rr) {
            const int gr = mt * 16 + quad * 4 + rr;
            #pragma unroll
            for (int i = 0; i < 2; ++i) gl[gr][(6 + i) * 16 + col] = rz2[i][rr];
            #pragma unroll
            for (int i = 0; i < 4; ++i) {
                gl[gr][128 + i * 16 + col] = niA[i][rr];
                gl[gr][192 + i * 16 + col] = nhA[i][rr];
            }
        }
    }
    LGKM0(); SBAR(); SCHED0();   // barrier C: gate tiles visible

    // combine: 32 rows x 64 outputs, 8 per thread. R17: float4-vectorized
    // LDS/global/bias access (g0 is 32B-aligned within rows; gl row stride
    // 1040B and fstate row 256B are 16B-aligned). Same arithmetic per
    // element -> absmax unchanged.
    {
        const int r  = threadIdx.x >> 3;
        const int g0 = (threadIdx.x & 7) * 8;
        const size_t gw = (size_t)(fbase + r) * 64 + g0;
        float fr[8], fz[8], fi[8], fh[8], fo[8];
        float br[8], bz[8], bi2[8], bh2[8];
        *(float4*)&fr[0] = *(const float4*)&gl[r][g0];
        *(float4*)&fr[4] = *(const float4*)&gl[r][g0 + 4];
        *(float4*)&fz[0] = *(const float4*)&gl[r][64 + g0];
        *(float4*)&fz[4] = *(const float4*)&gl[r][64 + g0 + 4];
        *(float4*)&fi[0] = *(const float4*)&gl[r][128 + g0];
        *(float4*)&fi[4] = *(const float4*)&gl[r][128 + g0 + 4];
        *(float4*)&fh[0] = *(const float4*)&gl[r][192 + g0];
        *(float4*)&fh[4] = *(const float4*)&gl[r][192 + g0 + 4];
        *(float4*)&fo[0] = *(const float4*)&fstate[gw];
        *(float4*)&fo[4] = *(const float4*)&fstate[gw + 4];
        *(float4*)&br[0] = *(const float4*)&bsum[g0];
        *(float4*)&br[4] = *(const float4*)&bsum[g0 + 4];
        *(float4*)&bz[0] = *(const float4*)&bsum[64 + g0];
        *(float4*)&bz[4] = *(const float4*)&bsum[64 + g0 + 4];
        *(float4*)&bi2[0] = *(const float4*)&bih[128 + g0];
        *(float4*)&bi2[4] = *(const float4*)&bih[128 + g0 + 4];
        *(float4*)&bh2[0] = *(const float4*)&bhh[128 + g0];
        *(float4*)&bh2[4] = *(const float4*)&bhh[128 + g0 + 4];
        float res[8];
        #pragma unroll
        for (int j = 0; j < 8; ++j) {
            float rv = sigm(fr[j] + br[j]);
            float zv = sigm(fz[j] + bz[j]);
            float nv = tanh_f(fi[j] + bi2[j] + rv * (fh[j] + bh2[j]));
            res[j] = (1.f - zv) * nv + zv * fo[j];
        }
        *(float4*)&fstate[gw]     = *(float4*)&res[0];
        *(float4*)&fstate[gw + 4] = *(float4*)&res[4];
    }
}

// ---------- MFMA GRU: h = GRU(nm, h), bf16 hi/lo, 4 waves x 16 rows ----------
// (var nodes only; nzero=NN re-zeroes nm for next step's f2v atomics.)
__global__ __launch_bounds__(256, 3)
void k_gru_mfma(float* __restrict__ nm,
                const unsigned short* __restrict__ wih_h, const unsigned short* __restrict__ wih_l,
                const unsigned short* __restrict__ whh_h, const unsigned short* __restrict__ whh_l,
                const float* __restrict__ bsum,          // bih+bhh [192]
                const float* __restrict__ bih, const float* __restrict__ bhh,
                float* __restrict__ hst, int count, int nzero)
{
    __shared__ float Hs[64][68];              // 17.4 KB, stride-68 conflict-free
    const int lane = threadIdx.x & 63;
    const int wv   = threadIdx.x >> 6;        // 0..3
    const int quad = lane >> 4;
    const int col  = lane & 15;
    const int base = blockIdx.x * 64;

    float4 am[4], ah[4];
    {
        int ra = base + wv * 16 + col;
        ra = ra < count ? ra : count - 1;
        const float4* pm = (const float4*)(nm + (size_t)ra * 64);
        const float4* ph = (const float4*)(hst + (size_t)ra * 64);
        am[0] = pm[quad * 2];     am[1] = pm[quad * 2 + 1];
        am[2] = pm[8 + quad * 2]; am[3] = pm[8 + quad * 2 + 1];
        ah[0] = ph[quad * 2];     ah[1] = ph[quad * 2 + 1];
        ah[2] = ph[8 + quad * 2]; ah[3] = ph[8 + quad * 2 + 1];
    }
    float bsr[4], bsz[4], bin_[4], bhn[4];
    #pragma unroll
    for (int t = 0; t < 4; ++t) {
        int g = t * 16 + col;
        bsr[t] = bsum[g]; bsz[t] = bsum[64 + g];
        bin_[t] = bih[128 + g]; bhn[t] = bhh[128 + g];
    }
    {
        int rowl = wv * 16 + col;
        *(float4*)(&Hs[rowl][quad * 8])          = ah[0];
        *(float4*)(&Hs[rowl][quad * 8 + 4])      = ah[1];
        *(float4*)(&Hs[rowl][32 + quad * 8])     = ah[2];
        *(float4*)(&Hs[rowl][32 + quad * 8 + 4]) = ah[3];
    }

    f32x4 rz[8], ni[4], nh[4];
    #pragma unroll
    for (int t = 0; t < 8; ++t) rz[t] = (f32x4){0.f, 0.f, 0.f, 0.f};
    #pragma unroll
    for (int t = 0; t < 4; ++t) {
        ni[t] = (f32x4){0.f, 0.f, 0.f, 0.f};
        nh[t] = (f32x4){0.f, 0.f, 0.f, 0.f};
    }

    #pragma unroll
    for (int ck = 0; ck < 2; ++ck) {
        short8 mhi, mlo, hhi, hlo;
        {
            float xv[8];
            f4pair_to8(am[ck * 2], am[ck * 2 + 1], xv);
            split8(xv, mhi, mlo);
            f4pair_to8(ah[ck * 2], ah[ck * 2 + 1], xv);
            split8(xv, hhi, hlo);
        }
        const unsigned short* ih = wih_h + (size_t)(ck * 12) * 512 + lane * 8;
        const unsigned short* il = wih_l + (size_t)(ck * 12) * 512 + lane * 8;
        const unsigned short* hh = whh_h + (size_t)(ck * 12) * 512 + lane * 8;
        const unsigned short* hl = whh_l + (size_t)(ck * 12) * 512 + lane * 8;
        PRIO1();
        #pragma unroll
        for (int tn = 0; tn < 8; ++tn) {
            short8 bihh = *(const short8*)(ih + tn * 512);
            short8 bihl = *(const short8*)(il + tn * 512);
            short8 bhhh = *(const short8*)(hh + tn * 512);
            short8 bhhl = *(const short8*)(hl + tn * 512);
            rz[tn] = __builtin_amdgcn_mfma_f32_16x16x32_bf16(mhi, bihh, rz[tn], 0, 0, 0);
            rz[tn] = __builtin_amdgcn_mfma_f32_16x16x32_bf16(mhi, bihl, rz[tn], 0, 0, 0);
            rz[tn] = __builtin_amdgcn_mfma_f32_16x16x32_bf16(mlo, bihh, rz[tn], 0, 0, 0);
            rz[tn] = __builtin_amdgcn_mfma_f32_16x16x32_bf16(hhi, bhhh, rz[tn], 0, 0, 0);
            rz[tn] = __builtin_amdgcn_mfma_f32_16x16x32_bf16(hhi, bhhl, rz[tn], 0, 0, 0);
            rz[tn] = __builtin_amdgcn_mfma_f32_16x16x32_bf16(hlo, bhhh, rz[tn], 0, 0, 0);
        }
        #pragma unroll
        for (int tn = 8; tn < 12; ++tn) {
            short8 bihh = *(const short8*)(ih + tn * 512);
            short8 bihl = *(const short8*)(il + tn * 512);
            short8 bhhh = *(const short8*)(hh + tn * 512);
            short8 bhhl = *(const short8*)(hl + tn * 512);
            ni[tn - 8] = __builtin_amdgcn_mfma_f32_16x16x32_bf16(mhi, bihh, ni[tn - 8], 0, 0, 0);
            ni[tn - 8] = __builtin_amdgcn_mfma_f32_16x16x32_bf16(mhi, bihl, ni[tn - 8], 0, 0, 0);
            ni[tn - 8] = __builtin_amdgcn_mfma_f32_16x16x32_bf16(mlo, bihh, ni[tn - 8], 0, 0, 0);
            nh[tn - 8] = __builtin_amdgcn_mfma_f32_16x16x32_bf16(hhi, bhhh, nh[tn - 8], 0, 0, 0);
            nh[tn - 8] = __builtin_amdgcn_mfma_f32_16x16x32_bf16(hhi, bhhl, nh[tn - 8], 0, 0, 0);
            nh[tn - 8] = __builtin_amdgcn_mfma_f32_16x16x32_bf16(hlo, bhhh, nh[tn - 8], 0, 0, 0);
        }
        PRIO0();
    }

    #pragma unroll
    for (int rr = 0; rr < 4; ++rr) {
        int rowl = wv * 16 + quad * 4 + rr;
        int grow = base + rowl;
        bool ok = grow < count;
        #pragma unroll
        for (int t = 0; t < 4; ++t) {
            int g = t * 16 + col;
            float rv = sigm(rz[t][rr] + bsr[t]);
            float zv = sigm(rz[4 + t][rr] + bsz[t]);
            float nv = tanh_f(ni[t][rr] + bin_[t] + rv * (nh[t][rr] + bhn[t]));
            if (ok) {
                float ho = Hs[rowl][g];
                hst[(size_t)grow * 64 + g] = (1.f - zv) * nv + zv * ho;
            }
            if (grow < nzero) nm[(size_t)grow * 64 + g] = 0.f;
        }
    }
}

// ---------- readout (unchanged) ----------
__global__ __launch_bounds__(256, 3)
void k_readout(const float* __restrict__ vh,
               const float* __restrict__ w1t, const float* __restrict__ b1,
               const float* __restrict__ w2t, const float* __restrict__ b2,
               const float* __restrict__ w3, const float* __restrict__ b3,
               float* __restrict__ out)
{
    __shared__ float H[HRDIM][64];
    const int lane = threadIdx.x & 63;
    const int wv   = __builtin_amdgcn_readfirstlane(threadIdx.x >> 6);
    const int n0 = blockIdx.x * 64 + lane;
    const int n  = n0 < NN ? n0 : NN - 1;
    const float4* px = (const float4*)(vh + (size_t)n * 64);

    const int j1 = 32 * wv;
    float acc[32];
    #pragma unroll
    for (int j = 0; j < 32; ++j) acc[j] = b1[j1 + j];
    #pragma unroll 4
    for (int q = 0; q < 16; ++q) {
        float4 x4 = px[q];
        const float* wa = w1t + (4 * q + 0) * HRDIM + j1;
        const float* wb = w1t + (4 * q + 1) * HRDIM + j1;
        const float* wc = w1t + (4 * q + 2) * HRDIM + j1;
        const float* wd = w1t + (4 * q + 3) * HRDIM + j1;
        #pragma unroll
        for (int j = 0; j < 32; ++j) {
            acc[j] = fmaf(wa[j], x4.x, acc[j]);
            acc[j] = fmaf(wb[j], x4.y, acc[j]);
            acc[j] = fmaf(wc[j], x4.z, acc[j]);
            acc[j] = fmaf(wd[j], x4.w, acc[j]);
        }
    }
    #pragma unroll
    for (int j = 0; j < 32; ++j) H[j1 + j][lane] = fmaxf(acc[j], 0.f);
    __syncthreads();

    #pragma unroll
    for (int j = 0; j < 32; ++j) acc[j] = b2[j1 + j];
    #pragma unroll 4
    for (int k = 0; k < HRDIM; ++k) {
        float xk = H[k][lane];
        const float* wr = w2t + k * HRDIM + j1;
        #pragma unroll
        for (int j = 0; j < 32; ++j)
            acc[j] = fmaf(wr[j], xk, acc[j]);
    }
    __syncthreads();
    #pragma unroll
    for (int j = 0; j < 32; ++j) H[j1 + j][lane] = fmaxf(acc[j], 0.f);
    __syncthreads();

    if (wv == 0 && n0 < NN) {
        float l0 = b3[0], l1 = b3[1];
        #pragma unroll 8
        for (int k = 0; k < HRDIM; ++k) {
            float hk = H[k][lane];
            l0 = fmaf(w3[k],         hk, l0);
            l1 = fmaf(w3[HRDIM + k], hk, l1);
        }
        float mx = fmaxf(l0, l1);
        float e0 = __expf(l0 - mx), e1 = __expf(l1 - mx);
        float inv = 1.f / (e0 + e1);
        out[2 * n + 0] = e0 * inv;
        out[2 * n + 1] = e1 * inv;
    }
}

// ---------- host ----------
extern "C" void kernel_launch(void* const* d_in, const int* in_sizes, int n_in,
                              void* d_out, int out_size, void* d_ws, size_t ws_size,
                              hipStream_t stream)
{
    float* var_h = (float*)d_ws;
    float* fac_h = var_h + 640000;
    float* nm    = fac_h + 5120000;
    float* ro_t  = nm + 5120000;            // 24,576 f32
    float* bsum  = ro_t + 24576;            // 384 f32 (2 x 192)
    unsigned short* pk = (unsigned short*)(bsum + 384); // 278,528 shorts

    const int*   f2v_row  = (const int*)d_in[0];
    const int*   f2v_col  = (const int*)d_in[1];
    const int*   v2f_row  = (const int*)d_in[2];
    const int*   v2f_col  = (const int*)d_in[3];
    const float* f2v_feat = (const float*)d_in[4];
    const float* v2f_feat = (const float*)d_in[5];
    const float* W[26];
    for (int j = 0; j < 26; ++j) W[j] = (const float*)d_in[6 + j];
    (void)f2v_row; (void)v2f_col;

    float* T[NTR];
    unsigned short* P[12];
    unsigned short* G[8];
    {
        size_t off = 0;
        int esz[3] = { 20480, 16384, 8192 };
        for (int d = 0; d < 2; ++d)
            for (int m = 0; m < 3; ++m) {
                P[d * 6 + m * 2 + 0] = pk + off; off += esz[m];
                P[d * 6 + m * 2 + 1] = pk + off; off += esz[m];
            }
        for (int t = 0; t < 8; ++t) { G[t] = pk + off; off += 12288; }
    }

    SArgs sa;
    {
        // pack streams
        const float* src[NPK] = { W[0], W[2], W[4], W[6], W[8], W[10],
                                  W[12], W[13], W[16], W[17] };
        int N[NPK]  = { HMDIM, HMDIM, SDIM,  HMDIM, HMDIM, SDIM,  192, 192, 192, 192 };
        int K[NPK]  = { KIN,   HMDIM, HMDIM, KIN,   HMDIM, HMDIM, SDIM, SDIM, SDIM, SDIM };
        int CK[NPK] = { 5,     4,     4,     5,     4,     4,     2,   2,   2,   2 };
        unsigned short* hi[NPK] = { P[0], P[2], P[4], P[6], P[8], P[10],
                                    G[0], G[2], G[4], G[6] };
        unsigned short* lo[NPK] = { P[1], P[3], P[5], P[7], P[9], P[11],
                                    G[1], G[3], G[5], G[7] };
        for (int t = 0; t < NPK; ++t) {
            sa.psrc[t] = src[t]; sa.N[t] = N[t]; sa.K[t] = K[t]; sa.CK[t] = CK[t];
            sa.phi[t] = hi[t];   sa.plo[t] = lo[t];
        }
        // transposes
        const float* tsrc[NTR] = { W[20], W[22] };
        int R[NTR] = { HRDIM, HRDIM };
        int C[NTR] = { SDIM, HRDIM };
        size_t toff = 0;
        for (int t = 0; t < NTR; ++t) {
            sa.tsrc[t] = tsrc[t]; sa.R[t] = R[t]; sa.C[t] = C[t];
            T[t] = ro_t + toff; sa.tdst[t] = T[t];
            toff += (size_t)R[t] * C[t];
        }
        // bsum
        sa.bih0 = W[14]; sa.bhh0 = W[15]; sa.o0 = bsum;
        sa.bih1 = W[18]; sa.bhh1 = W[19]; sa.o1 = bsum + 192;
        // zero (states + nm)
        sa.zp = var_h; sa.zn = 640000 + 5120000 + 5120000;
    }
    k_setup<<<NPK + NTR + 1 + NZB, 256, 0, stream>>>(sa);

    for (int s = 0; s < NSTEPS; ++s) {
        // fac -> var messages into nm[node] (atomic scatter); var GRU reads
        // nm and re-zeroes rows [0,NN) for the next step's atomics.
        k_edge_mfma<<<NE / 64, 256, 0, stream>>>(
            fac_h, var_h, f2v_col, f2v_feat,
            P[0], P[1], P[2], P[3], P[4], P[5],
            W[1], W[3], W[5], nm);
        k_gru_mfma<<<(NN + 63) / 64, 256, 0, stream>>>(
            nm, G[0], G[1], G[2], G[3], bsum, W[14], W[15], var_h, NN, NN);
        // var -> fac messages + fac GRU, fused (factor messages stay in LDS;
        // nm untouched in the factor region).
        k_edge_gru_fused<<<NE / 64, 256, 0, stream>>>(
            var_h, fac_h, v2f_row, v2f_feat,
            P[6], P[7], P[8], P[9], P[10], P[11],
            W[7], W[9], W[11],
            G[4], G[5], G[6], G[7], bsum + 192, W[18], W[19]);
    }
    k_readout<<<(NN + 63) / 64, 256, 0, stream>>>(
        var_h, T[0], W[21], T[1], W[23], W[24], W[25],
        (float*)d_out);
}